// Round 8
// baseline (171.788 us; speedup 1.0000x reference)
//
#include <hip/hip_runtime.h>
#include <hip/hip_bf16.h>
#include <cmath>

typedef __bf16 bf16;
typedef __attribute__((ext_vector_type(4))) __bf16 bf16x4;
typedef __attribute__((ext_vector_type(8))) __bf16 bf16x8;
typedef __attribute__((ext_vector_type(4))) float f32x4;

#define B_ 2
#define S_ 2048
#define D_ 1024
#define N_ 16
#define H_ 64
// 0.125 * log2(e): folded into Q at projection so QK^T emits exp2-domain scores
#define QSCALE 0.18033688011112042f

__device__ __forceinline__ void gload16(const bf16* g, bf16* l) {
  __builtin_amdgcn_global_load_lds(
      (const __attribute__((address_space(1))) void*)(g),
      (__attribute__((address_space(3))) void*)(l), 16, 0, 0);
}

__device__ __forceinline__ f32x4 mfma16(bf16x8 a, bf16x8 b, f32x4 c) {
  return __builtin_amdgcn_mfma_f32_16x16x32_bf16(a, b, c, 0, 0, 0);
}

__device__ __forceinline__ f32x4 zero4() {
  f32x4 v = {0.0f, 0.0f, 0.0f, 0.0f};
  return v;
}

// ---------------------------------------------------------------------------
// fp32 -> bf16 elementwise convert. 8 elems/thread.
// ---------------------------------------------------------------------------
__global__ __launch_bounds__(256) void cvt_kernel(
    const float* __restrict__ in, bf16* __restrict__ out, int n8) {
  int id = blockIdx.x * 256 + threadIdx.x;
  if (id >= n8) return;
  const float4* p = (const float4*)(in + (size_t)id * 8);
  float4 v0 = p[0], v1 = p[1];
  bf16x8 o;
  o[0] = (bf16)v0.x; o[1] = (bf16)v0.y; o[2] = (bf16)v0.z; o[3] = (bf16)v0.w;
  o[4] = (bf16)v1.x; o[5] = (bf16)v1.y; o[6] = (bf16)v1.z; o[7] = (bf16)v1.w;
  *(bf16x8*)(out + (size_t)id * 8) = o;
}

// ---------------------------------------------------------------------------
// Merged QKV weight transpose: head z (0..47) of {Wk,Wq,Wv}, [1024][64] fp32
// -> [64][1024] bf16 at out + z*64*1024. grid (16, 1, 48), block 256.
// ---------------------------------------------------------------------------
__global__ __launch_bounds__(256) void qkvw_transpose_kernel(
    const float* __restrict__ Wk, const float* __restrict__ Wq,
    const float* __restrict__ Wv, bf16* __restrict__ out) {
  __shared__ bf16 t[64][72];
  const int z = blockIdx.z;
  const float* W = (z < 16) ? Wk : (z < 32) ? Wq : Wv;
  const float* ing = W + (size_t)(z & 15) * (1024 * 64);
  bf16* outg = out + (size_t)z * (64 * 1024);
  const int r0 = blockIdx.x * 64;
  const int t8 = threadIdx.x & 7, trow = threadIdx.x >> 3;
#pragma unroll
  for (int p = 0; p < 2; ++p) {
    int r = trow + p * 32;
    const float4* src = (const float4*)(ing + (size_t)(r0 + r) * 64 + t8 * 8);
    float4 v0 = src[0], v1 = src[1];
    bf16x8 o;
    o[0] = (bf16)v0.x; o[1] = (bf16)v0.y; o[2] = (bf16)v0.z; o[3] = (bf16)v0.w;
    o[4] = (bf16)v1.x; o[5] = (bf16)v1.y; o[6] = (bf16)v1.z; o[7] = (bf16)v1.w;
    *(bf16x8*)(&t[r][t8 * 8]) = o;
  }
  __syncthreads();
#pragma unroll
  for (int p = 0; p < 2; ++p) {
    int c = trow + p * 32;
    bf16x8 v;
#pragma unroll
    for (int j = 0; j < 8; ++j) v[j] = t[t8 * 8 + j][c];
    *(bf16x8*)(outg + (size_t)c * 1024 + r0 + t8 * 8) = v;
  }
}

// ---------------------------------------------------------------------------
// Transpose fp32 [R][C] -> bf16 [C][R], G matrices. grid (R/64, C/64, G), 256.
// ---------------------------------------------------------------------------
__global__ __launch_bounds__(256) void transpose_f32bf16_kernel(
    const float* __restrict__ in, bf16* __restrict__ out, int R, int C) {
  __shared__ bf16 t[64][72];
  const size_t mat = (size_t)R * C;
  const float* ing = in + (size_t)blockIdx.z * mat;
  bf16* outg = out + (size_t)blockIdx.z * mat;
  const int r0 = blockIdx.x * 64, c0 = blockIdx.y * 64;
  const int t8 = threadIdx.x & 7, trow = threadIdx.x >> 3;
#pragma unroll
  for (int p = 0; p < 2; ++p) {
    int r = trow + p * 32;
    const float4* src = (const float4*)(ing + (size_t)(r0 + r) * C + c0 + t8 * 8);
    float4 v0 = src[0], v1 = src[1];
    bf16x8 o;
    o[0] = (bf16)v0.x; o[1] = (bf16)v0.y; o[2] = (bf16)v0.z; o[3] = (bf16)v0.w;
    o[4] = (bf16)v1.x; o[5] = (bf16)v1.y; o[6] = (bf16)v1.z; o[7] = (bf16)v1.w;
    *(bf16x8*)(&t[r][t8 * 8]) = o;
  }
  __syncthreads();
#pragma unroll
  for (int p = 0; p < 2; ++p) {
    int c = trow + p * 32;
    bf16x8 v;
#pragma unroll
    for (int j = 0; j < 8; ++j) v[j] = t[t8 * 8 + j][c];
    *(bf16x8*)(outg + (size_t)(c0 + c) * R + r0 + t8 * 8) = v;
  }
}

// ---------------------------------------------------------------------------
// Transpose bf16 [R][C] -> bf16 [C][R], G matrices.
// ---------------------------------------------------------------------------
__global__ __launch_bounds__(256) void transpose_bf16_kernel(
    const bf16* __restrict__ in, bf16* __restrict__ out, int R, int C) {
  __shared__ bf16 t[64][72];
  const size_t mat = (size_t)R * C;
  const bf16* ing = in + (size_t)blockIdx.z * mat;
  bf16* outg = out + (size_t)blockIdx.z * mat;
  const int r0 = blockIdx.x * 64, c0 = blockIdx.y * 64;
  const int t8 = threadIdx.x & 7, trow = threadIdx.x >> 3;
#pragma unroll
  for (int p = 0; p < 2; ++p) {
    int r = trow + p * 32;
    bf16x8 v = *(const bf16x8*)(ing + (size_t)(r0 + r) * C + c0 + t8 * 8);
    *(bf16x8*)(&t[r][t8 * 8]) = v;
  }
  __syncthreads();
#pragma unroll
  for (int p = 0; p < 2; ++p) {
    int c = trow + p * 32;
    bf16x8 v;
#pragma unroll
    for (int j = 0; j < 8; ++j) v[j] = t[t8 * 8 + j][c];
    *(bf16x8*)(outg + (size_t)(c0 + c) * R + r0 + t8 * 8) = v;
  }
}

// ---------------------------------------------------------------------------
// Suffix-V (32-row segments): Suf[hd][q][h] = sum_{k>q} V[hd][k][h].
// Suf is bf16, computed IN-PLACE over Vp (strict read-element-then-write).
// ---------------------------------------------------------------------------
__global__ __launch_bounds__(256) void sufv_tot_kernel(
    const bf16* __restrict__ Vp, float* __restrict__ tot) {
  __shared__ float red[4][64];
  const int hd = blockIdx.x, seg = blockIdx.y;
  const int h = threadIdx.x & 63, sub = threadIdx.x >> 6;
  const bf16* Vh = Vp + (size_t)hd * S_ * H_;
  float a = 0.0f;
  const int k0 = seg * 32 + sub * 8;
#pragma unroll
  for (int k = 0; k < 8; ++k) a += (float)Vh[(size_t)(k0 + k) * H_ + h];
  red[sub][h] = a;
  __syncthreads();
  if (sub == 0)
    tot[(hd * 64 + seg) * 64 + h] = red[0][h] + red[1][h] + red[2][h] + red[3][h];
}

__global__ __launch_bounds__(64) void sufv_scan_kernel(
    bf16* __restrict__ VS, const float* __restrict__ tot) {
  const int hd = blockIdx.x, seg = blockIdx.y, h = threadIdx.x;
  bf16* Vh = VS + (size_t)hd * S_ * H_;  // in: V, out: Suf (in-place)
  float a = 0.0f;
  for (int s2 = seg + 1; s2 < 64; ++s2) a += tot[(hd * 64 + s2) * 64 + h];
  for (int k = seg * 32 + 31; k >= seg * 32; --k) {
    const float v = (float)Vh[(size_t)k * H_ + h];  // read BEFORE overwrite
    Vh[(size_t)k * H_ + h] = (bf16)a;
    a += v;
  }
}

// ---------------------------------------------------------------------------
// QKV projection GEMM (swizzled LDS): A[4096x1024] bf16 x Bt[z].
// z==1 (queries) epilogue pre-scales by QSCALE = 0.125*log2(e).
// ---------------------------------------------------------------------------
__global__ __launch_bounds__(256) void gemm_proj_kernel(
    const bf16* __restrict__ A, const bf16* __restrict__ Wt_base,
    const float* __restrict__ bk, const float* __restrict__ bq,
    const float* __restrict__ bv, bf16* __restrict__ proj_base) {
  __shared__ bf16 As[128 * 64];
  __shared__ bf16 Bs[128 * 64];
  const int z = blockIdx.z;
  const bf16* Bt = Wt_base + (size_t)z * (1024 * 1024);
  const float* bias = (z == 0) ? bk : (z == 1 ? bq : bv);
  const float osc = (z == 1) ? QSCALE : 1.0f;
  bf16* Out = proj_base + (size_t)z * ((size_t)B_ * N_ * S_ * H_);
  const int tid = threadIdx.x;
  const int w = tid >> 6, l = tid & 63, lan = l & 15, grp = l >> 4;
  const int mb = (w >> 1) * 64, nb = (w & 1) * 64;
  const int m0 = blockIdx.y * 128, n0 = blockIdx.x * 128;
  const int lrow8 = l >> 3;
  const int swl = ((l & 7) ^ lrow8) * 8;
  const int l7 = lan & 7;

  f32x4 acc[4][4];
#pragma unroll
  for (int i = 0; i < 4; ++i)
#pragma unroll
    for (int j = 0; j < 4; ++j) acc[i][j] = zero4();

  for (int kb = 0; kb < 1024; kb += 64) {
    __syncthreads();
#pragma unroll
    for (int i = 0; i < 4; ++i) {
      int ch = w * 4 + i;
      gload16(A + (size_t)(m0 + ch * 8 + lrow8) * 1024 + kb + swl, As + ch * 512);
      gload16(Bt + (size_t)(n0 + ch * 8 + lrow8) * 1024 + kb + swl, Bs + ch * 512);
    }
    __syncthreads();
#pragma unroll
    for (int kk = 0; kk < 2; ++kk) {
      bf16x8 a[4], b[4];
#pragma unroll
      for (int mf = 0; mf < 4; ++mf)
        a[mf] = *(const bf16x8*)(As + (mb + mf * 16 + lan) * 64 + (((grp + kk * 4) ^ l7) << 3));
#pragma unroll
      for (int nf = 0; nf < 4; ++nf)
        b[nf] = *(const bf16x8*)(Bs + (nb + nf * 16 + lan) * 64 + (((grp + kk * 4) ^ l7) << 3));
#pragma unroll
      for (int mf = 0; mf < 4; ++mf)
#pragma unroll
        for (int nf = 0; nf < 4; ++nf)
          acc[mf][nf] = mfma16(a[mf], b[nf], acc[mf][nf]);
    }
  }
#pragma unroll
  for (int nf = 0; nf < 4; ++nf) {
    int c = n0 + nb + nf * 16 + lan;
    float bs = bias[c];
    int n = c >> 6, h = c & 63;
#pragma unroll
    for (int mf = 0; mf < 4; ++mf) {
#pragma unroll
      for (int r = 0; r < 4; ++r) {
        int m = m0 + mb + mf * 16 + grp * 4 + r;
        int b = m >> 11, s = m & 2047;
        Out[((size_t)((b * N_ + n) * S_ + s)) * H_ + h] = (bf16)((acc[mf][nf][r] + bs) * osc);
      }
    }
  }
}

// ---------------------------------------------------------------------------
// Output projection GEMM (swizzled LDS): weighted[4096x1024] x WoT -> fp32 out.
// ---------------------------------------------------------------------------
__global__ __launch_bounds__(256) void gemm_out_kernel(
    const bf16* __restrict__ A, const bf16* __restrict__ Bt,
    const float* __restrict__ bias, float* __restrict__ Out) {
  __shared__ bf16 As[128 * 64];
  __shared__ bf16 Bs[128 * 64];
  const int tid = threadIdx.x;
  const int w = tid >> 6, l = tid & 63, lan = l & 15, grp = l >> 4;
  const int mb = (w >> 1) * 64, nb = (w & 1) * 64;
  const int m0 = blockIdx.y * 128, n0 = blockIdx.x * 128;
  const int lrow8 = l >> 3;
  const int swl = ((l & 7) ^ lrow8) * 8;
  const int l7 = lan & 7;

  f32x4 acc[4][4];
#pragma unroll
  for (int i = 0; i < 4; ++i)
#pragma unroll
    for (int j = 0; j < 4; ++j) acc[i][j] = zero4();

  for (int kb = 0; kb < 1024; kb += 64) {
    __syncthreads();
#pragma unroll
    for (int i = 0; i < 4; ++i) {
      int ch = w * 4 + i;
      gload16(A + (size_t)(m0 + ch * 8 + lrow8) * 1024 + kb + swl, As + ch * 512);
      gload16(Bt + (size_t)(n0 + ch * 8 + lrow8) * 1024 + kb + swl, Bs + ch * 512);
    }
    __syncthreads();
#pragma unroll
    for (int kk = 0; kk < 2; ++kk) {
      bf16x8 a[4], b[4];
#pragma unroll
      for (int mf = 0; mf < 4; ++mf)
        a[mf] = *(const bf16x8*)(As + (mb + mf * 16 + lan) * 64 + (((grp + kk * 4) ^ l7) << 3));
#pragma unroll
      for (int nf = 0; nf < 4; ++nf)
        b[nf] = *(const bf16x8*)(Bs + (nb + nf * 16 + lan) * 64 + (((grp + kk * 4) ^ l7) << 3));
#pragma unroll
      for (int mf = 0; mf < 4; ++mf)
#pragma unroll
        for (int nf = 0; nf < 4; ++nf)
          acc[mf][nf] = mfma16(a[mf], b[nf], acc[mf][nf]);
    }
  }
#pragma unroll
  for (int nf = 0; nf < 4; ++nf) {
    int c = n0 + nb + nf * 16 + lan;
    float bs = bias[c];
#pragma unroll
    for (int mf = 0; mf < 4; ++mf) {
#pragma unroll
      for (int r = 0; r < 4; ++r) {
        int m = m0 + mb + mf * 16 + grp * 4 + r;
        Out[(size_t)m * 1024 + c] = acc[mf][nf][r] + bs;
      }
    }
  }
}

// ---------------------------------------------------------------------------
// Attention (split-k, balanced; single barrier/tile; ones-MFMA psum):
//   quarter 0 (bi<256):  x=15-wv, k-tiles [0, x+1)     -> fp32 partial A
//   quarter 1 (bi<512):  x=15-wv, k-tiles [x+1, 2x+2)  -> fp32 partial B
//   quarter 2 (bi<768):  x=wv,    k-tiles [0, 2x+2)    -> final Wtd rows
// Q is pre-scaled by QSCALE, so p = exp2(raw QK^T). grid 768, block 256.
// ---------------------------------------------------------------------------
__global__ __launch_bounds__(256) void attn_kernel(
    const bf16* __restrict__ Qp, const bf16* __restrict__ Kp,
    const bf16* __restrict__ Vt, const bf16* __restrict__ Suf,
    bf16* __restrict__ Wtd, float* __restrict__ PoA, float* __restrict__ PoB,
    float* __restrict__ PpA, float* __restrict__ PpB) {
  __shared__ bf16 Ks[2][64 * 64];
  __shared__ bf16 Vs[2][64 * 64];
  __shared__ bf16 Ps[4][32 * 72];
  const int tid = threadIdx.x;
  const int w = tid >> 6, l = tid & 63, lan = l & 15, grp = l >> 4;
  const int bi = blockIdx.x;
  const int qq = bi >> 8;
  const int j = bi & 255;
  const int hd = j & 31, wv = j >> 5;
  int x, t0, t1;
  if (qq == 0)      { x = 15 - wv; t0 = 0;     t1 = x + 1; }
  else if (qq == 1) { x = 15 - wv; t0 = x + 1; t1 = 2 * x + 2; }
  else              { x = wv;      t0 = 0;     t1 = 2 * x + 2; }
  const int qw = x * 128 + w * 32;
  const bf16* Qh = Qp + (size_t)hd * S_ * H_;
  const bf16* Kh = Kp + (size_t)hd * S_ * H_;
  const bf16* Vh = Vt + (size_t)hd * H_ * S_;
  const bf16* Sufh = Suf + (size_t)hd * S_ * H_;
  const int lrow8 = l >> 3;
  const int swl = ((l & 7) ^ lrow8) * 8;
  const int l7 = lan & 7;
  bf16x8 vones;
#pragma unroll
  for (int i = 0; i < 8; ++i) vones[i] = (bf16)1.0f;

#define STAGE(buf, kb_)                                                        \
  do {                                                                         \
    _Pragma("unroll") for (int i2 = 0; i2 < 2; ++i2) {                         \
      int ch = w * 2 + i2;                                                     \
      gload16(Kh + (size_t)((kb_) + ch * 8 + lrow8) * H_ + swl,                \
              &Ks[buf][ch * 512]);                                             \
      gload16(Vh + (size_t)(ch * 8 + lrow8) * S_ + (kb_) + swl,                \
              &Vs[buf][ch * 512]);                                             \
    }                                                                          \
  } while (0)

  // Q fragments (B-operand for swapped QK^T: n=lan=q, k=grp*8+j (+32*kf))
  bf16x8 qa[2][2];
#pragma unroll
  for (int qt = 0; qt < 2; ++qt)
#pragma unroll
    for (int kf = 0; kf < 2; ++kf)
      qa[qt][kf] = *(const bf16x8*)(Qh + (size_t)(qw + qt * 16 + lan) * H_ + grp * 8 + kf * 32);

  f32x4 o[2][4];
  f32x4 psf[2];  // row-sum accumulator via ones-MFMA (C-layout rows = q)
#pragma unroll
  for (int qt = 0; qt < 2; ++qt) {
    psf[qt] = zero4();
#pragma unroll
    for (int hf = 0; hf < 4; ++hf) o[qt][hf] = zero4();
  }

  bf16* Pw = &Ps[w][0];

  STAGE(0, t0 * 64);
  for (int tt = t0; tt < t1; ++tt) {
    const int kb = tt * 64;
    const int cur = (tt - t0) & 1;
    // Single sync point: my tile-tt loads drained, then block-wide barrier
    // (=> everyone's loads visible AND everyone done reading buf[cur^1]).
    asm volatile("s_waitcnt vmcnt(0)" ::: "memory");
    __builtin_amdgcn_s_barrier();
    if (tt + 1 < t1) STAGE(cur ^ 1, kb + 64);

    if (kb <= qw + 31) {
      const bf16* Kc = &Ks[cur][0];
      const bf16* Vc = &Vs[cur][0];

      // --- swapped QK^T: s2[k2][qt], col=lan=q, row=grp*4+r=k ---
      f32x4 s2[4][2];
#pragma unroll
      for (int k2 = 0; k2 < 4; ++k2)
#pragma unroll
        for (int qt = 0; qt < 2; ++qt) s2[k2][qt] = zero4();
      __builtin_amdgcn_s_setprio(1);
#pragma unroll
      for (int kf = 0; kf < 2; ++kf) {
        bf16x8 kfr[4];
#pragma unroll
        for (int k2 = 0; k2 < 4; ++k2)
          kfr[k2] = *(const bf16x8*)(Kc + (k2 * 16 + lan) * 64 + (((grp + kf * 4) ^ l7) << 3));
#pragma unroll
        for (int k2 = 0; k2 < 4; ++k2)
#pragma unroll
          for (int qt = 0; qt < 2; ++qt)
            s2[k2][qt] = mfma16(kfr[k2], qa[qt][kf], s2[k2][qt]);
      }
      __builtin_amdgcn_s_setprio(0);

      // --- p = exp2(s) (Q pre-scaled), diag-mask, pack -> one b64 write ---
      const bool maskt = (kb + 63 > qw);
#pragma unroll
      for (int qt = 0; qt < 2; ++qt) {
        const int q_g = qw + qt * 16 + lan;
#pragma unroll
        for (int k2 = 0; k2 < 4; ++k2) {
          f32x4 p;
#pragma unroll
          for (int r = 0; r < 4; ++r) p[r] = exp2f(s2[k2][qt][r]);
          if (maskt) {
            const int kg0 = kb + k2 * 16 + grp * 4;
#pragma unroll
            for (int r = 0; r < 4; ++r)
              if (kg0 + r > q_g) p[r] = 0.0f;
          }
          unsigned plo, phi;
          asm("v_cvt_pk_bf16_f32 %0, %1, %2" : "=v"(plo) : "v"(p[0]), "v"(p[1]));
          asm("v_cvt_pk_bf16_f32 %0, %1, %2" : "=v"(phi) : "v"(p[2]), "v"(p[3]));
          uint2 u; u.x = plo; u.y = phi;
          *(uint2*)(Pw + (qt * 16 + lan) * 72 + k2 * 16 + grp * 4) = u;
        }
      }

      // --- PV + psum (ones-MFMA rides on the same pa registers) ---
      __builtin_amdgcn_s_setprio(1);
#pragma unroll
      for (int ks = 0; ks < 2; ++ks) {
        bf16x8 pa[2], vb[4];
#pragma unroll
        for (int qt = 0; qt < 2; ++qt)
          pa[qt] = *(const bf16x8*)(Pw + (qt * 16 + lan) * 72 + grp * 8 + ks * 32);
#pragma unroll
        for (int hf = 0; hf < 4; ++hf)
          vb[hf] = *(const bf16x8*)(Vc + (hf * 16 + lan) * 64 + (((grp + ks * 4) ^ l7) << 3));
#pragma unroll
        for (int qt = 0; qt < 2; ++qt) {
#pragma unroll
          for (int hf = 0; hf < 4; ++hf)
            o[qt][hf] = mfma16(pa[qt], vb[hf], o[qt][hf]);
          psf[qt] = mfma16(pa[qt], vones, psf[qt]);
        }
      }
      __builtin_amdgcn_s_setprio(0);
    }
  }
#undef STAGE

  if (qq == 2) {
    // final: o = (o_causal + SufV) / (psum + (2047-q)); psf row=grp*4+r=q
    const size_t outbase = (size_t)(hd >> 4) * S_ * (N_ * H_) + (size_t)(hd & 15) * H_;
#pragma unroll
    for (int qt = 0; qt < 2; ++qt) {
#pragma unroll
      for (int r = 0; r < 4; ++r) {
        const int q_g = qw + qt * 16 + grp * 4 + r;
        const float inv = 1.0f / (psf[qt][r] + (float)(2047 - q_g));
#pragma unroll
        for (int hf = 0; hf < 4; ++hf) {
          const int h = hf * 16 + lan;
          const float suf = (float)Sufh[(size_t)q_g * H_ + h];
          Wtd[outbase + (size_t)q_g * (N_ * H_) + h] = (bf16)((o[qt][hf][r] + suf) * inv);
        }
      }
    }
  } else {
    // partial: raw fp32 o + row psums (psf identical across lan)
    float* Po = (qq == 0) ? PoA : PoB;
    float* Pp = (qq == 0) ? PpA : PpB;
    const int pb = (hd * 8 + (x - 8)) * 128 + w * 32;
#pragma unroll
    for (int qt = 0; qt < 2; ++qt) {
#pragma unroll
      for (int r = 0; r < 4; ++r) {
        const int rl = qt * 16 + grp * 4 + r;
        if (lan == 0) Pp[pb + rl] = psf[qt][r];
#pragma unroll
        for (int hf = 0; hf < 4; ++hf)
          Po[(size_t)(pb + rl) * 64 + hf * 16 + lan] = o[qt][hf][r];
      }
    }
  }
}

// ---------------------------------------------------------------------------
// Combine: for x in 8..15, Wtd = (PoA + PoB + Suf) / (PpA + PpB + 2047-q).
// ---------------------------------------------------------------------------
__global__ __launch_bounds__(256) void combine_kernel(
    const float* __restrict__ PoA, const float* __restrict__ PoB,
    const float* __restrict__ PpA, const float* __restrict__ PpB,
    const bf16* __restrict__ Suf, bf16* __restrict__ Wtd) {
  const int hd = blockIdx.x >> 3, xi = blockIdx.x & 7;
  const int x = xi + 8;
  const int pb = (hd * 8 + xi) * 128;
  const size_t outbase = (size_t)(hd >> 4) * S_ * (N_ * H_) + (size_t)(hd & 15) * H_;
#pragma unroll
  for (int it = 0; it < 8; ++it) {
    const int e = it * 256 + threadIdx.x;  // 0..2047 float4 units
    const int rl = e >> 4, h4 = (e & 15) * 4;
    const int q_g = x * 128 + rl;
    const float Z = PpA[pb + rl] + PpB[pb + rl] + (float)(2047 - q_g);
    const float inv = 1.0f / Z;
    const float4 a = *(const float4*)(PoA + (size_t)(pb + rl) * 64 + h4);
    const float4 b = *(const float4*)(PoB + (size_t)(pb + rl) * 64 + h4);
    const bf16x4 s4 = *(const bf16x4*)(Suf + ((size_t)hd * S_ + q_g) * 64 + h4);
    bf16x4 ov;
    ov[0] = (bf16)((a.x + b.x + (float)s4[0]) * inv);
    ov[1] = (bf16)((a.y + b.y + (float)s4[1]) * inv);
    ov[2] = (bf16)((a.z + b.z + (float)s4[2]) * inv);
    ov[3] = (bf16)((a.w + b.w + (float)s4[3]) * inv);
    *(bf16x4*)(Wtd + outbase + (size_t)q_g * (N_ * H_) + h4) = ov;
  }
}

// ---------------------------------------------------------------------------
extern "C" void kernel_launch(void* const* d_in, const int* in_sizes, int n_in,
                              void* d_out, int out_size, void* d_ws, size_t ws_size,
                              hipStream_t stream) {
  const float* residual = (const float*)d_in[0];
  const float* Wk = (const float*)d_in[1];
  const float* Wq = (const float*)d_in[2];
  const float* Wv = (const float*)d_in[3];
  const float* Wo = (const float*)d_in[4];
  const float* Bk = (const float*)d_in[5];
  const float* Bq = (const float*)d_in[6];
  const float* Bv = (const float*)d_in[7];
  const float* Bo = (const float*)d_in[8];
  float* outp = (float*)d_out;

  // ws layout (peak 48MB — proven safe; do NOT exceed):
  //   [ 0.. 8) Abf (cvt out, gemm_proj A)        -> Wtd (attn/combine out)
  //   [ 8..10) Wot (live to end)
  //   [10..16) Wkt (gemm_proj B)                 -> PpA, PpB, tot
  //   [16..24) Kp   [24..32) Qp
  //   [32..40) Vp (proj V) -> in-place Suf (bf16) via sufv_scan
  //   [40..48) Vtp
  // d_out (16MB fp32): PoA [0..8MB) + PoB [8..16MB) until gemm_out overwrites.
  char* ws = (char*)d_ws;
  const size_t MB = 1024 * 1024;
  bf16* Abf = (bf16*)(ws + 0 * MB);
  bf16* Wot = (bf16*)(ws + 8 * MB);
  bf16* Wkt = (bf16*)(ws + 10 * MB);
  bf16* Kp  = (bf16*)(ws + 16 * MB);
  bf16* Qp  = (bf16*)(ws + 24 * MB);
  bf16* Vp  = (bf16*)(ws + 32 * MB);
  bf16* Vtp = (bf16*)(ws + 40 * MB);
  bf16* Wtd = Abf;                                   // dead after gemm_proj
  float* PpA = (float*)(ws + 10 * MB);               // [32][8][128] (128KB)
  float* PpB = (float*)(ws + 10 * MB + 128 * 1024);  // (128KB)
  float* tot = (float*)(ws + 10 * MB + 256 * 1024);  // [32][64][64] (512KB)
  bf16* Suf = Vp;                                    // in-place over Vp
  float* PoA = (float*)d_out;                        // [32][8][128][64] (8MB)
  float* PoB = (float*)d_out + 2 * 1024 * 1024;      // (8MB)
  (void)in_sizes; (void)n_in; (void)out_size; (void)ws_size;

  // residual fp32 -> bf16
  cvt_kernel<<<2048, 256, 0, stream>>>(residual, Abf, (B_ * S_ * D_) / 8);

  // weight transposes
  qkvw_transpose_kernel<<<dim3(16, 1, 48), 256, 0, stream>>>(Wk, Wq, Wv, Wkt);
  transpose_f32bf16_kernel<<<dim3(16, 16, 1), 256, 0, stream>>>(Wo, Wot, 1024, 1024);

  // QKV projections (queries pre-scaled by QSCALE)
  gemm_proj_kernel<<<dim3(8, 32, 3), 256, 0, stream>>>(Abf, Wkt, Bk, Bq, Bv, Kp);

  // V consumers BEFORE the in-place suffix scan:
  sufv_tot_kernel<<<dim3(32, 64), 256, 0, stream>>>(Vp, tot);
  transpose_bf16_kernel<<<dim3(32, 1, 32), 256, 0, stream>>>(Vp, Vtp, 2048, 64);
  // in-place: Vp becomes Suf (bf16)
  sufv_scan_kernel<<<dim3(32, 64), 64, 0, stream>>>(Vp, tot);

  // attention: split-k, balanced (34 tiles per CU triple)
  attn_kernel<<<768, 256, 0, stream>>>(Qp, Kp, Vtp, Suf, Wtd, PoA, PoB, PpA, PpB);

  // combine halves for x >= 8
  combine_kernel<<<256, 256, 0, stream>>>(PoA, PoB, PpA, PpB, Suf, Wtd);

  // output projection -> fp32 d_out (overwrites PoA/PoB scratch)
  gemm_out_kernel<<<dim3(8, 32, 1), 256, 0, stream>>>(Wtd, Wot, Bo, outp);
}

// Round 9
// 169.668 us; speedup vs baseline: 1.0125x; 1.0125x over previous
//
#include <hip/hip_runtime.h>
#include <hip/hip_bf16.h>
#include <cmath>

typedef __bf16 bf16;
typedef __attribute__((ext_vector_type(4))) __bf16 bf16x4;
typedef __attribute__((ext_vector_type(8))) __bf16 bf16x8;
typedef __attribute__((ext_vector_type(4))) float f32x4;

#define B_ 2
#define S_ 2048
#define D_ 1024
#define N_ 16
#define H_ 64
// 0.125 * log2(e): folded into Q at projection so QK^T emits exp2-domain scores
#define QSCALE 0.18033688011112042f

__device__ __forceinline__ void gload16(const bf16* g, bf16* l) {
  __builtin_amdgcn_global_load_lds(
      (const __attribute__((address_space(1))) void*)(g),
      (__attribute__((address_space(3))) void*)(l), 16, 0, 0);
}

__device__ __forceinline__ f32x4 mfma16(bf16x8 a, bf16x8 b, f32x4 c) {
  return __builtin_amdgcn_mfma_f32_16x16x32_bf16(a, b, c, 0, 0, 0);
}

__device__ __forceinline__ f32x4 zero4() {
  f32x4 v = {0.0f, 0.0f, 0.0f, 0.0f};
  return v;
}

// ---------------------------------------------------------------------------
// fp32 -> bf16 elementwise convert. 8 elems/thread.
// ---------------------------------------------------------------------------
__global__ __launch_bounds__(256) void cvt_kernel(
    const float* __restrict__ in, bf16* __restrict__ out, int n8) {
  int id = blockIdx.x * 256 + threadIdx.x;
  if (id >= n8) return;
  const float4* p = (const float4*)(in + (size_t)id * 8);
  float4 v0 = p[0], v1 = p[1];
  bf16x8 o;
  o[0] = (bf16)v0.x; o[1] = (bf16)v0.y; o[2] = (bf16)v0.z; o[3] = (bf16)v0.w;
  o[4] = (bf16)v1.x; o[5] = (bf16)v1.y; o[6] = (bf16)v1.z; o[7] = (bf16)v1.w;
  *(bf16x8*)(out + (size_t)id * 8) = o;
}

// ---------------------------------------------------------------------------
// Merged QKV weight transpose: head z (0..47) of {Wk,Wq,Wv}, [1024][64] fp32
// -> [64][1024] bf16 at out + z*64*1024. grid (16, 1, 48), block 256.
// ---------------------------------------------------------------------------
__global__ __launch_bounds__(256) void qkvw_transpose_kernel(
    const float* __restrict__ Wk, const float* __restrict__ Wq,
    const float* __restrict__ Wv, bf16* __restrict__ out) {
  __shared__ bf16 t[64][72];
  const int z = blockIdx.z;
  const float* W = (z < 16) ? Wk : (z < 32) ? Wq : Wv;
  const float* ing = W + (size_t)(z & 15) * (1024 * 64);
  bf16* outg = out + (size_t)z * (64 * 1024);
  const int r0 = blockIdx.x * 64;
  const int t8 = threadIdx.x & 7, trow = threadIdx.x >> 3;
#pragma unroll
  for (int p = 0; p < 2; ++p) {
    int r = trow + p * 32;
    const float4* src = (const float4*)(ing + (size_t)(r0 + r) * 64 + t8 * 8);
    float4 v0 = src[0], v1 = src[1];
    bf16x8 o;
    o[0] = (bf16)v0.x; o[1] = (bf16)v0.y; o[2] = (bf16)v0.z; o[3] = (bf16)v0.w;
    o[4] = (bf16)v1.x; o[5] = (bf16)v1.y; o[6] = (bf16)v1.z; o[7] = (bf16)v1.w;
    *(bf16x8*)(&t[r][t8 * 8]) = o;
  }
  __syncthreads();
#pragma unroll
  for (int p = 0; p < 2; ++p) {
    int c = trow + p * 32;
    bf16x8 v;
#pragma unroll
    for (int j = 0; j < 8; ++j) v[j] = t[t8 * 8 + j][c];
    *(bf16x8*)(outg + (size_t)c * 1024 + r0 + t8 * 8) = v;
  }
}

// ---------------------------------------------------------------------------
// Transpose fp32 [R][C] -> bf16 [C][R], G matrices. grid (R/64, C/64, G), 256.
// ---------------------------------------------------------------------------
__global__ __launch_bounds__(256) void transpose_f32bf16_kernel(
    const float* __restrict__ in, bf16* __restrict__ out, int R, int C) {
  __shared__ bf16 t[64][72];
  const size_t mat = (size_t)R * C;
  const float* ing = in + (size_t)blockIdx.z * mat;
  bf16* outg = out + (size_t)blockIdx.z * mat;
  const int r0 = blockIdx.x * 64, c0 = blockIdx.y * 64;
  const int t8 = threadIdx.x & 7, trow = threadIdx.x >> 3;
#pragma unroll
  for (int p = 0; p < 2; ++p) {
    int r = trow + p * 32;
    const float4* src = (const float4*)(ing + (size_t)(r0 + r) * C + c0 + t8 * 8);
    float4 v0 = src[0], v1 = src[1];
    bf16x8 o;
    o[0] = (bf16)v0.x; o[1] = (bf16)v0.y; o[2] = (bf16)v0.z; o[3] = (bf16)v0.w;
    o[4] = (bf16)v1.x; o[5] = (bf16)v1.y; o[6] = (bf16)v1.z; o[7] = (bf16)v1.w;
    *(bf16x8*)(&t[r][t8 * 8]) = o;
  }
  __syncthreads();
#pragma unroll
  for (int p = 0; p < 2; ++p) {
    int c = trow + p * 32;
    bf16x8 v;
#pragma unroll
    for (int j = 0; j < 8; ++j) v[j] = t[t8 * 8 + j][c];
    *(bf16x8*)(outg + (size_t)(c0 + c) * R + r0 + t8 * 8) = v;
  }
}

// ---------------------------------------------------------------------------
// Transpose bf16 [R][C] -> bf16 [C][R], G matrices.
// ---------------------------------------------------------------------------
__global__ __launch_bounds__(256) void transpose_bf16_kernel(
    const bf16* __restrict__ in, bf16* __restrict__ out, int R, int C) {
  __shared__ bf16 t[64][72];
  const size_t mat = (size_t)R * C;
  const bf16* ing = in + (size_t)blockIdx.z * mat;
  bf16* outg = out + (size_t)blockIdx.z * mat;
  const int r0 = blockIdx.x * 64, c0 = blockIdx.y * 64;
  const int t8 = threadIdx.x & 7, trow = threadIdx.x >> 3;
#pragma unroll
  for (int p = 0; p < 2; ++p) {
    int r = trow + p * 32;
    bf16x8 v = *(const bf16x8*)(ing + (size_t)(r0 + r) * C + c0 + t8 * 8);
    *(bf16x8*)(&t[r][t8 * 8]) = v;
  }
  __syncthreads();
#pragma unroll
  for (int p = 0; p < 2; ++p) {
    int c = trow + p * 32;
    bf16x8 v;
#pragma unroll
    for (int j = 0; j < 8; ++j) v[j] = t[t8 * 8 + j][c];
    *(bf16x8*)(outg + (size_t)(c0 + c) * R + r0 + t8 * 8) = v;
  }
}

// ---------------------------------------------------------------------------
// Suffix-V (32-row segments): Suf[hd][q][h] = sum_{k>q} V[hd][k][h].
// Suf is bf16, computed IN-PLACE over Vp (strict read-element-then-write).
// ---------------------------------------------------------------------------
__global__ __launch_bounds__(256) void sufv_tot_kernel(
    const bf16* __restrict__ Vp, float* __restrict__ tot) {
  __shared__ float red[4][64];
  const int hd = blockIdx.x, seg = blockIdx.y;
  const int h = threadIdx.x & 63, sub = threadIdx.x >> 6;
  const bf16* Vh = Vp + (size_t)hd * S_ * H_;
  float a = 0.0f;
  const int k0 = seg * 32 + sub * 8;
#pragma unroll
  for (int k = 0; k < 8; ++k) a += (float)Vh[(size_t)(k0 + k) * H_ + h];
  red[sub][h] = a;
  __syncthreads();
  if (sub == 0)
    tot[(hd * 64 + seg) * 64 + h] = red[0][h] + red[1][h] + red[2][h] + red[3][h];
}

__global__ __launch_bounds__(64) void sufv_scan_kernel(
    bf16* __restrict__ VS, const float* __restrict__ tot) {
  const int hd = blockIdx.x, seg = blockIdx.y, h = threadIdx.x;
  bf16* Vh = VS + (size_t)hd * S_ * H_;  // in: V, out: Suf (in-place)
  float a = 0.0f;
  for (int s2 = seg + 1; s2 < 64; ++s2) a += tot[(hd * 64 + s2) * 64 + h];
  for (int k = seg * 32 + 31; k >= seg * 32; --k) {
    const float v = (float)Vh[(size_t)k * H_ + h];  // read BEFORE overwrite
    Vh[(size_t)k * H_ + h] = (bf16)a;
    a += v;
  }
}

// ---------------------------------------------------------------------------
// Merged QKV projection GEMM (swizzled LDS): A[4096x1024] bf16 x Wt[3072x1024].
// One dispatch, N=3072; 128-col blocks never straddle a z-boundary.
// z==1 (queries) epilogue pre-scales by QSCALE. grid (24, 32), block 256.
// ---------------------------------------------------------------------------
__global__ __launch_bounds__(256) void gemm_proj_kernel(
    const bf16* __restrict__ A, const bf16* __restrict__ Bt,
    const float* __restrict__ bk, const float* __restrict__ bq,
    const float* __restrict__ bv, bf16* __restrict__ proj_base) {
  __shared__ bf16 As[128 * 64];
  __shared__ bf16 Bs[128 * 64];
  const int tid = threadIdx.x;
  const int w = tid >> 6, l = tid & 63, lan = l & 15, grp = l >> 4;
  const int mb = (w >> 1) * 64, nb = (w & 1) * 64;
  const int m0 = blockIdx.y * 128, n0 = blockIdx.x * 128;
  const int zc = n0 >> 10;  // constant per block (1024 % 128 == 0)
  const float* bias = (zc == 0) ? bk : (zc == 1 ? bq : bv);
  const float osc = (zc == 1) ? QSCALE : 1.0f;
  bf16* Out = proj_base + (size_t)zc * ((size_t)B_ * N_ * S_ * H_);
  const int lrow8 = l >> 3;
  const int swl = ((l & 7) ^ lrow8) * 8;
  const int l7 = lan & 7;

  f32x4 acc[4][4];
#pragma unroll
  for (int i = 0; i < 4; ++i)
#pragma unroll
    for (int j = 0; j < 4; ++j) acc[i][j] = zero4();

  for (int kb = 0; kb < 1024; kb += 64) {
    __syncthreads();
#pragma unroll
    for (int i = 0; i < 4; ++i) {
      int ch = w * 4 + i;
      gload16(A + (size_t)(m0 + ch * 8 + lrow8) * 1024 + kb + swl, As + ch * 512);
      gload16(Bt + (size_t)(n0 + ch * 8 + lrow8) * 1024 + kb + swl, Bs + ch * 512);
    }
    __syncthreads();
#pragma unroll
    for (int kk = 0; kk < 2; ++kk) {
      bf16x8 a[4], b[4];
#pragma unroll
      for (int mf = 0; mf < 4; ++mf)
        a[mf] = *(const bf16x8*)(As + (mb + mf * 16 + lan) * 64 + (((grp + kk * 4) ^ l7) << 3));
#pragma unroll
      for (int nf = 0; nf < 4; ++nf)
        b[nf] = *(const bf16x8*)(Bs + (nb + nf * 16 + lan) * 64 + (((grp + kk * 4) ^ l7) << 3));
#pragma unroll
      for (int mf = 0; mf < 4; ++mf)
#pragma unroll
        for (int nf = 0; nf < 4; ++nf)
          acc[mf][nf] = mfma16(a[mf], b[nf], acc[mf][nf]);
    }
  }
#pragma unroll
  for (int nf = 0; nf < 4; ++nf) {
    int c10 = (n0 + nb + nf * 16 + lan) & 1023;
    float bs = bias[c10];
    int n = c10 >> 6, h = c10 & 63;
#pragma unroll
    for (int mf = 0; mf < 4; ++mf) {
#pragma unroll
      for (int r = 0; r < 4; ++r) {
        int m = m0 + mb + mf * 16 + grp * 4 + r;
        int b = m >> 11, s = m & 2047;
        Out[((size_t)((b * N_ + n) * S_ + s)) * H_ + h] = (bf16)((acc[mf][nf][r] + bs) * osc);
      }
    }
  }
}

// ---------------------------------------------------------------------------
// Output projection GEMM (swizzled LDS): weighted[4096x1024] x WoT -> fp32 out.
// ---------------------------------------------------------------------------
__global__ __launch_bounds__(256) void gemm_out_kernel(
    const bf16* __restrict__ A, const bf16* __restrict__ Bt,
    const float* __restrict__ bias, float* __restrict__ Out) {
  __shared__ bf16 As[128 * 64];
  __shared__ bf16 Bs[128 * 64];
  const int tid = threadIdx.x;
  const int w = tid >> 6, l = tid & 63, lan = l & 15, grp = l >> 4;
  const int mb = (w >> 1) * 64, nb = (w & 1) * 64;
  const int m0 = blockIdx.y * 128, n0 = blockIdx.x * 128;
  const int lrow8 = l >> 3;
  const int swl = ((l & 7) ^ lrow8) * 8;
  const int l7 = lan & 7;

  f32x4 acc[4][4];
#pragma unroll
  for (int i = 0; i < 4; ++i)
#pragma unroll
    for (int j = 0; j < 4; ++j) acc[i][j] = zero4();

  for (int kb = 0; kb < 1024; kb += 64) {
    __syncthreads();
#pragma unroll
    for (int i = 0; i < 4; ++i) {
      int ch = w * 4 + i;
      gload16(A + (size_t)(m0 + ch * 8 + lrow8) * 1024 + kb + swl, As + ch * 512);
      gload16(Bt + (size_t)(n0 + ch * 8 + lrow8) * 1024 + kb + swl, Bs + ch * 512);
    }
    __syncthreads();
#pragma unroll
    for (int kk = 0; kk < 2; ++kk) {
      bf16x8 a[4], b[4];
#pragma unroll
      for (int mf = 0; mf < 4; ++mf)
        a[mf] = *(const bf16x8*)(As + (mb + mf * 16 + lan) * 64 + (((grp + kk * 4) ^ l7) << 3));
#pragma unroll
      for (int nf = 0; nf < 4; ++nf)
        b[nf] = *(const bf16x8*)(Bs + (nb + nf * 16 + lan) * 64 + (((grp + kk * 4) ^ l7) << 3));
#pragma unroll
      for (int mf = 0; mf < 4; ++mf)
#pragma unroll
        for (int nf = 0; nf < 4; ++nf)
          acc[mf][nf] = mfma16(a[mf], b[nf], acc[mf][nf]);
    }
  }
#pragma unroll
  for (int nf = 0; nf < 4; ++nf) {
    int c = n0 + nb + nf * 16 + lan;
    float bs = bias[c];
#pragma unroll
    for (int mf = 0; mf < 4; ++mf) {
#pragma unroll
      for (int r = 0; r < 4; ++r) {
        int m = m0 + mb + mf * 16 + grp * 4 + r;
        Out[(size_t)m * 1024 + c] = acc[mf][nf][r] + bs;
      }
    }
  }
}

// ---------------------------------------------------------------------------
// Attention (split-k, balanced; R7 sync skeleton: STAGE-first + counted vmcnt
// + two barriers; R8 compute: ones-MFMA psum, exp2-domain Q):
//   quarter 0 (bi<256):  x=15-wv, k-tiles [0, x+1)     -> fp32 partial A
//   quarter 1 (bi<512):  x=15-wv, k-tiles [x+1, 2x+2)  -> fp32 partial B
//   quarter 2 (bi<768):  x=wv,    k-tiles [0, 2x+2)    -> final Wtd rows
// grid 768, block 256 (4 waves x 32 q-rows).
// ---------------------------------------------------------------------------
__global__ __launch_bounds__(256) void attn_kernel(
    const bf16* __restrict__ Qp, const bf16* __restrict__ Kp,
    const bf16* __restrict__ Vt, const bf16* __restrict__ Suf,
    bf16* __restrict__ Wtd, float* __restrict__ PoA, float* __restrict__ PoB,
    float* __restrict__ PpA, float* __restrict__ PpB) {
  __shared__ bf16 Ks[2][64 * 64];
  __shared__ bf16 Vs[2][64 * 64];
  __shared__ bf16 Ps[4][32 * 72];
  const int tid = threadIdx.x;
  const int w = tid >> 6, l = tid & 63, lan = l & 15, grp = l >> 4;
  const int bi = blockIdx.x;
  const int qq = bi >> 8;
  const int j = bi & 255;
  const int hd = j & 31, wv = j >> 5;
  int x, t0, t1;
  if (qq == 0)      { x = 15 - wv; t0 = 0;     t1 = x + 1; }
  else if (qq == 1) { x = 15 - wv; t0 = x + 1; t1 = 2 * x + 2; }
  else              { x = wv;      t0 = 0;     t1 = 2 * x + 2; }
  const int qw = x * 128 + w * 32;
  const bf16* Qh = Qp + (size_t)hd * S_ * H_;
  const bf16* Kh = Kp + (size_t)hd * S_ * H_;
  const bf16* Vh = Vt + (size_t)hd * H_ * S_;
  const bf16* Sufh = Suf + (size_t)hd * S_ * H_;
  const int lrow8 = l >> 3;
  const int swl = ((l & 7) ^ lrow8) * 8;
  const int l7 = lan & 7;
  bf16x8 vones;
#pragma unroll
  for (int i = 0; i < 8; ++i) vones[i] = (bf16)1.0f;

#define STAGE(buf, kb_)                                                        \
  do {                                                                         \
    _Pragma("unroll") for (int i2 = 0; i2 < 2; ++i2) {                         \
      int ch = w * 2 + i2;                                                     \
      gload16(Kh + (size_t)((kb_) + ch * 8 + lrow8) * H_ + swl,                \
              &Ks[buf][ch * 512]);                                             \
      gload16(Vh + (size_t)(ch * 8 + lrow8) * S_ + (kb_) + swl,                \
              &Vs[buf][ch * 512]);                                             \
    }                                                                          \
  } while (0)

  // Q fragments (B-operand for swapped QK^T: n=lan=q, k=grp*8+j (+32*kf))
  bf16x8 qa[2][2];
#pragma unroll
  for (int qt = 0; qt < 2; ++qt)
#pragma unroll
    for (int kf = 0; kf < 2; ++kf)
      qa[qt][kf] = *(const bf16x8*)(Qh + (size_t)(qw + qt * 16 + lan) * H_ + grp * 8 + kf * 32);

  f32x4 o[2][4];
  f32x4 psf[2];  // row-sum accumulator via ones-MFMA (C-layout rows = q)
#pragma unroll
  for (int qt = 0; qt < 2; ++qt) {
    psf[qt] = zero4();
#pragma unroll
    for (int hf = 0; hf < 4; ++hf) o[qt][hf] = zero4();
  }

  bf16* Pw = &Ps[w][0];

  STAGE(0, t0 * 64);
  for (int tt = t0; tt < t1; ++tt) {
    const int kb = tt * 64;
    const int cur = (tt - t0) & 1;
    // R7 skeleton: prefetch issues BEFORE the wait; counted vmcnt keeps the
    // next tile's loads in flight across the barrier (T3/T4).
    if (tt + 1 < t1) {
      STAGE(cur ^ 1, kb + 64);
      asm volatile("s_waitcnt vmcnt(4)" ::: "memory");
    } else {
      asm volatile("s_waitcnt vmcnt(0)" ::: "memory");
    }
    __builtin_amdgcn_s_barrier();

    if (kb <= qw + 31) {
      const bf16* Kc = &Ks[cur][0];
      const bf16* Vc = &Vs[cur][0];

      // --- swapped QK^T: s2[k2][qt], col=lan=q, row=grp*4+r=k ---
      f32x4 s2[4][2];
#pragma unroll
      for (int k2 = 0; k2 < 4; ++k2)
#pragma unroll
        for (int qt = 0; qt < 2; ++qt) s2[k2][qt] = zero4();
      __builtin_amdgcn_s_setprio(1);
#pragma unroll
      for (int kf = 0; kf < 2; ++kf) {
        bf16x8 kfr[4];
#pragma unroll
        for (int k2 = 0; k2 < 4; ++k2)
          kfr[k2] = *(const bf16x8*)(Kc + (k2 * 16 + lan) * 64 + (((grp + kf * 4) ^ l7) << 3));
#pragma unroll
        for (int k2 = 0; k2 < 4; ++k2)
#pragma unroll
          for (int qt = 0; qt < 2; ++qt)
            s2[k2][qt] = mfma16(kfr[k2], qa[qt][kf], s2[k2][qt]);
      }
      __builtin_amdgcn_s_setprio(0);

      // --- p = exp2(s) (Q pre-scaled), diag-mask, pack -> one b64 write ---
      const bool maskt = (kb + 63 > qw);
#pragma unroll
      for (int qt = 0; qt < 2; ++qt) {
        const int q_g = qw + qt * 16 + lan;
#pragma unroll
        for (int k2 = 0; k2 < 4; ++k2) {
          f32x4 p;
#pragma unroll
          for (int r = 0; r < 4; ++r) p[r] = exp2f(s2[k2][qt][r]);
          if (maskt) {
            const int kg0 = kb + k2 * 16 + grp * 4;
#pragma unroll
            for (int r = 0; r < 4; ++r)
              if (kg0 + r > q_g) p[r] = 0.0f;
          }
          unsigned plo, phi;
          asm("v_cvt_pk_bf16_f32 %0, %1, %2" : "=v"(plo) : "v"(p[0]), "v"(p[1]));
          asm("v_cvt_pk_bf16_f32 %0, %1, %2" : "=v"(phi) : "v"(p[2]), "v"(p[3]));
          uint2 u; u.x = plo; u.y = phi;
          *(uint2*)(Pw + (qt * 16 + lan) * 72 + k2 * 16 + grp * 4) = u;
        }
      }

      // --- PV + psum (ones-MFMA rides on the same pa registers) ---
      __builtin_amdgcn_s_setprio(1);
#pragma unroll
      for (int ks = 0; ks < 2; ++ks) {
        bf16x8 pa[2], vb[4];
#pragma unroll
        for (int qt = 0; qt < 2; ++qt)
          pa[qt] = *(const bf16x8*)(Pw + (qt * 16 + lan) * 72 + grp * 8 + ks * 32);
#pragma unroll
        for (int hf = 0; hf < 4; ++hf)
          vb[hf] = *(const bf16x8*)(Vc + (hf * 16 + lan) * 64 + (((grp + ks * 4) ^ l7) << 3));
#pragma unroll
        for (int qt = 0; qt < 2; ++qt) {
#pragma unroll
          for (int hf = 0; hf < 4; ++hf)
            o[qt][hf] = mfma16(pa[qt], vb[hf], o[qt][hf]);
          psf[qt] = mfma16(pa[qt], vones, psf[qt]);
        }
      }
      __builtin_amdgcn_s_setprio(0);
    }
    __builtin_amdgcn_s_barrier();
  }
#undef STAGE

  if (qq == 2) {
    // final: o = (o_causal + SufV) / (psum + (2047-q)); psf row=grp*4+r=q
    const size_t outbase = (size_t)(hd >> 4) * S_ * (N_ * H_) + (size_t)(hd & 15) * H_;
#pragma unroll
    for (int qt = 0; qt < 2; ++qt) {
#pragma unroll
      for (int r = 0; r < 4; ++r) {
        const int q_g = qw + qt * 16 + grp * 4 + r;
        const float inv = 1.0f / (psf[qt][r] + (float)(2047 - q_g));
#pragma unroll
        for (int hf = 0; hf < 4; ++hf) {
          const int h = hf * 16 + lan;
          const float suf = (float)Sufh[(size_t)q_g * H_ + h];
          Wtd[outbase + (size_t)q_g * (N_ * H_) + h] = (bf16)((o[qt][hf][r] + suf) * inv);
        }
      }
    }
  } else {
    // partial: raw fp32 o + row psums (psf identical across lan)
    float* Po = (qq == 0) ? PoA : PoB;
    float* Pp = (qq == 0) ? PpA : PpB;
    const int pb = (hd * 8 + (x - 8)) * 128 + w * 32;
#pragma unroll
    for (int qt = 0; qt < 2; ++qt) {
#pragma unroll
      for (int r = 0; r < 4; ++r) {
        const int rl = qt * 16 + grp * 4 + r;
        if (lan == 0) Pp[pb + rl] = psf[qt][r];
#pragma unroll
        for (int hf = 0; hf < 4; ++hf)
          Po[(size_t)(pb + rl) * 64 + hf * 16 + lan] = o[qt][hf][r];
      }
    }
  }
}

// ---------------------------------------------------------------------------
// Combine: for x in 8..15, Wtd = (PoA + PoB + Suf) / (PpA + PpB + 2047-q).
// ---------------------------------------------------------------------------
__global__ __launch_bounds__(256) void combine_kernel(
    const float* __restrict__ PoA, const float* __restrict__ PoB,
    const float* __restrict__ PpA, const float* __restrict__ PpB,
    const bf16* __restrict__ Suf, bf16* __restrict__ Wtd) {
  const int hd = blockIdx.x >> 3, xi = blockIdx.x & 7;
  const int x = xi + 8;
  const int pb = (hd * 8 + xi) * 128;
  const size_t outbase = (size_t)(hd >> 4) * S_ * (N_ * H_) + (size_t)(hd & 15) * H_;
#pragma unroll
  for (int it = 0; it < 8; ++it) {
    const int e = it * 256 + threadIdx.x;  // 0..2047 float4 units
    const int rl = e >> 4, h4 = (e & 15) * 4;
    const int q_g = x * 128 + rl;
    const float Z = PpA[pb + rl] + PpB[pb + rl] + (float)(2047 - q_g);
    const float inv = 1.0f / Z;
    const float4 a = *(const float4*)(PoA + (size_t)(pb + rl) * 64 + h4);
    const float4 b = *(const float4*)(PoB + (size_t)(pb + rl) * 64 + h4);
    const bf16x4 s4 = *(const bf16x4*)(Suf + ((size_t)hd * S_ + q_g) * 64 + h4);
    bf16x4 ov;
    ov[0] = (bf16)((a.x + b.x + (float)s4[0]) * inv);
    ov[1] = (bf16)((a.y + b.y + (float)s4[1]) * inv);
    ov[2] = (bf16)((a.z + b.z + (float)s4[2]) * inv);
    ov[3] = (bf16)((a.w + b.w + (float)s4[3]) * inv);
    *(bf16x4*)(Wtd + outbase + (size_t)q_g * (N_ * H_) + h4) = ov;
  }
}

// ---------------------------------------------------------------------------
extern "C" void kernel_launch(void* const* d_in, const int* in_sizes, int n_in,
                              void* d_out, int out_size, void* d_ws, size_t ws_size,
                              hipStream_t stream) {
  const float* residual = (const float*)d_in[0];
  const float* Wk = (const float*)d_in[1];
  const float* Wq = (const float*)d_in[2];
  const float* Wv = (const float*)d_in[3];
  const float* Wo = (const float*)d_in[4];
  const float* Bk = (const float*)d_in[5];
  const float* Bq = (const float*)d_in[6];
  const float* Bv = (const float*)d_in[7];
  const float* Bo = (const float*)d_in[8];
  float* outp = (float*)d_out;

  // ws layout (peak 48MB — proven safe; do NOT exceed):
  //   [ 0.. 8) Abf (cvt out, gemm_proj A)        -> Wtd (attn/combine out)
  //   [ 8..10) Wot (live to end)
  //   [10..16) Wkt (gemm_proj B, [3072][1024])   -> PpA, PpB, tot
  //   [16..24) Kp   [24..32) Qp
  //   [32..40) Vp (proj V) -> in-place Suf (bf16) via sufv_scan
  //   [40..48) Vtp
  // d_out (16MB fp32): PoA [0..8MB) + PoB [8..16MB) until gemm_out overwrites.
  char* ws = (char*)d_ws;
  const size_t MB = 1024 * 1024;
  bf16* Abf = (bf16*)(ws + 0 * MB);
  bf16* Wot = (bf16*)(ws + 8 * MB);
  bf16* Wkt = (bf16*)(ws + 10 * MB);
  bf16* Kp  = (bf16*)(ws + 16 * MB);
  bf16* Qp  = (bf16*)(ws + 24 * MB);
  bf16* Vp  = (bf16*)(ws + 32 * MB);
  bf16* Vtp = (bf16*)(ws + 40 * MB);
  bf16* Wtd = Abf;                                   // dead after gemm_proj
  float* PpA = (float*)(ws + 10 * MB);               // [32][8][128] (128KB)
  float* PpB = (float*)(ws + 10 * MB + 128 * 1024);  // (128KB)
  float* tot = (float*)(ws + 10 * MB + 256 * 1024);  // [32][64][64] (512KB)
  bf16* Suf = Vp;                                    // in-place over Vp
  float* PoA = (float*)d_out;                        // [32][8][128][64] (8MB)
  float* PoB = (float*)d_out + 2 * 1024 * 1024;      // (8MB)
  (void)in_sizes; (void)n_in; (void)out_size; (void)ws_size;

  // residual fp32 -> bf16
  cvt_kernel<<<2048, 256, 0, stream>>>(residual, Abf, (B_ * S_ * D_) / 8);

  // weight transposes
  qkvw_transpose_kernel<<<dim3(16, 1, 48), 256, 0, stream>>>(Wk, Wq, Wv, Wkt);
  transpose_f32bf16_kernel<<<dim3(16, 16, 1), 256, 0, stream>>>(Wo, Wot, 1024, 1024);

  // QKV projections — single merged dispatch, N=3072 (queries pre-scaled)
  gemm_proj_kernel<<<dim3(24, 32), 256, 0, stream>>>(Abf, Wkt, Bk, Bq, Bv, Kp);

  // V consumers BEFORE the in-place suffix scan:
  sufv_tot_kernel<<<dim3(32, 64), 256, 0, stream>>>(Vp, tot);
  transpose_bf16_kernel<<<dim3(32, 1, 32), 256, 0, stream>>>(Vp, Vtp, 2048, 64);
  // in-place: Vp becomes Suf (bf16)
  sufv_scan_kernel<<<dim3(32, 64), 64, 0, stream>>>(Vp, tot);

  // attention: split-k, balanced (34 tiles per CU triple)
  attn_kernel<<<768, 256, 0, stream>>>(Qp, Kp, Vtp, Suf, Wtd, PoA, PoB, PpA, PpB);

  // combine halves for x >= 8
  combine_kernel<<<256, 256, 0, stream>>>(PoA, PoB, PpA, PpB, Suf, Wtd);

  // output projection -> fp32 d_out (overwrites PoA/PoB scratch)
  gemm_out_kernel<<<dim3(8, 32, 1), 256, 0, stream>>>(Wtd, Wot, Bo, outp);
}

// Round 10
// 155.178 us; speedup vs baseline: 1.1070x; 1.0934x over previous
//
#include <hip/hip_runtime.h>
#include <hip/hip_bf16.h>
#include <cmath>

typedef __bf16 bf16;
typedef __attribute__((ext_vector_type(4))) __bf16 bf16x4;
typedef __attribute__((ext_vector_type(8))) __bf16 bf16x8;
typedef __attribute__((ext_vector_type(4))) float f32x4;

#define B_ 2
#define S_ 2048
#define D_ 1024
#define N_ 16
#define H_ 64
#define LOG2E 1.44269504088896340736f

__device__ __forceinline__ void gload16(const bf16* g, bf16* l) {
  __builtin_amdgcn_global_load_lds(
      (const __attribute__((address_space(1))) void*)(g),
      (__attribute__((address_space(3))) void*)(l), 16, 0, 0);
}

__device__ __forceinline__ f32x4 mfma16(bf16x8 a, bf16x8 b, f32x4 c) {
  return __builtin_amdgcn_mfma_f32_16x16x32_bf16(a, b, c, 0, 0, 0);
}

__device__ __forceinline__ f32x4 zero4() {
  f32x4 v = {0.0f, 0.0f, 0.0f, 0.0f};
  return v;
}

// ---------------------------------------------------------------------------
// fp32 -> bf16 elementwise convert. 8 elems/thread.
// ---------------------------------------------------------------------------
__global__ __launch_bounds__(256) void cvt_kernel(
    const float* __restrict__ in, bf16* __restrict__ out, int n8) {
  int id = blockIdx.x * 256 + threadIdx.x;
  if (id >= n8) return;
  const float4* p = (const float4*)(in + (size_t)id * 8);
  float4 v0 = p[0], v1 = p[1];
  bf16x8 o;
  o[0] = (bf16)v0.x; o[1] = (bf16)v0.y; o[2] = (bf16)v0.z; o[3] = (bf16)v0.w;
  o[4] = (bf16)v1.x; o[5] = (bf16)v1.y; o[6] = (bf16)v1.z; o[7] = (bf16)v1.w;
  *(bf16x8*)(out + (size_t)id * 8) = o;
}

// ---------------------------------------------------------------------------
// Merged QKV weight transpose: head z (0..47) of {Wk,Wq,Wv}, [1024][64] fp32
// -> [64][1024] bf16 at out + z*64*1024. grid (16, 1, 48), block 256.
// ---------------------------------------------------------------------------
__global__ __launch_bounds__(256) void qkvw_transpose_kernel(
    const float* __restrict__ Wk, const float* __restrict__ Wq,
    const float* __restrict__ Wv, bf16* __restrict__ out) {
  __shared__ bf16 t[64][72];
  const int z = blockIdx.z;
  const float* W = (z < 16) ? Wk : (z < 32) ? Wq : Wv;
  const float* ing = W + (size_t)(z & 15) * (1024 * 64);
  bf16* outg = out + (size_t)z * (64 * 1024);
  const int r0 = blockIdx.x * 64;
  const int t8 = threadIdx.x & 7, trow = threadIdx.x >> 3;
#pragma unroll
  for (int p = 0; p < 2; ++p) {
    int r = trow + p * 32;
    const float4* src = (const float4*)(ing + (size_t)(r0 + r) * 64 + t8 * 8);
    float4 v0 = src[0], v1 = src[1];
    bf16x8 o;
    o[0] = (bf16)v0.x; o[1] = (bf16)v0.y; o[2] = (bf16)v0.z; o[3] = (bf16)v0.w;
    o[4] = (bf16)v1.x; o[5] = (bf16)v1.y; o[6] = (bf16)v1.z; o[7] = (bf16)v1.w;
    *(bf16x8*)(&t[r][t8 * 8]) = o;
  }
  __syncthreads();
#pragma unroll
  for (int p = 0; p < 2; ++p) {
    int c = trow + p * 32;
    bf16x8 v;
#pragma unroll
    for (int j = 0; j < 8; ++j) v[j] = t[t8 * 8 + j][c];
    *(bf16x8*)(outg + (size_t)c * 1024 + r0 + t8 * 8) = v;
  }
}

// ---------------------------------------------------------------------------
// Transpose fp32 [R][C] -> bf16 [C][R], G matrices. grid (R/64, C/64, G), 256.
// ---------------------------------------------------------------------------
__global__ __launch_bounds__(256) void transpose_f32bf16_kernel(
    const float* __restrict__ in, bf16* __restrict__ out, int R, int C) {
  __shared__ bf16 t[64][72];
  const size_t mat = (size_t)R * C;
  const float* ing = in + (size_t)blockIdx.z * mat;
  bf16* outg = out + (size_t)blockIdx.z * mat;
  const int r0 = blockIdx.x * 64, c0 = blockIdx.y * 64;
  const int t8 = threadIdx.x & 7, trow = threadIdx.x >> 3;
#pragma unroll
  for (int p = 0; p < 2; ++p) {
    int r = trow + p * 32;
    const float4* src = (const float4*)(ing + (size_t)(r0 + r) * C + c0 + t8 * 8);
    float4 v0 = src[0], v1 = src[1];
    bf16x8 o;
    o[0] = (bf16)v0.x; o[1] = (bf16)v0.y; o[2] = (bf16)v0.z; o[3] = (bf16)v0.w;
    o[4] = (bf16)v1.x; o[5] = (bf16)v1.y; o[6] = (bf16)v1.z; o[7] = (bf16)v1.w;
    *(bf16x8*)(&t[r][t8 * 8]) = o;
  }
  __syncthreads();
#pragma unroll
  for (int p = 0; p < 2; ++p) {
    int c = trow + p * 32;
    bf16x8 v;
#pragma unroll
    for (int j = 0; j < 8; ++j) v[j] = t[t8 * 8 + j][c];
    *(bf16x8*)(outg + (size_t)(c0 + c) * R + r0 + t8 * 8) = v;
  }
}

// ---------------------------------------------------------------------------
// Transpose bf16 [R][C] -> bf16 [C][R], G matrices.
// ---------------------------------------------------------------------------
__global__ __launch_bounds__(256) void transpose_bf16_kernel(
    const bf16* __restrict__ in, bf16* __restrict__ out, int R, int C) {
  __shared__ bf16 t[64][72];
  const size_t mat = (size_t)R * C;
  const bf16* ing = in + (size_t)blockIdx.z * mat;
  bf16* outg = out + (size_t)blockIdx.z * mat;
  const int r0 = blockIdx.x * 64, c0 = blockIdx.y * 64;
  const int t8 = threadIdx.x & 7, trow = threadIdx.x >> 3;
#pragma unroll
  for (int p = 0; p < 2; ++p) {
    int r = trow + p * 32;
    bf16x8 v = *(const bf16x8*)(ing + (size_t)(r0 + r) * C + c0 + t8 * 8);
    *(bf16x8*)(&t[r][t8 * 8]) = v;
  }
  __syncthreads();
#pragma unroll
  for (int p = 0; p < 2; ++p) {
    int c = trow + p * 32;
    bf16x8 v;
#pragma unroll
    for (int j = 0; j < 8; ++j) v[j] = t[t8 * 8 + j][c];
    *(bf16x8*)(outg + (size_t)(c0 + c) * R + r0 + t8 * 8) = v;
  }
}

// ---------------------------------------------------------------------------
// Suffix-V (32-row segments): Suf[hd][q][h] = sum_{k>q} V[hd][k][h].
// Suf is bf16, computed IN-PLACE over Vp (strict read-element-then-write).
// ---------------------------------------------------------------------------
__global__ __launch_bounds__(256) void sufv_tot_kernel(
    const bf16* __restrict__ Vp, float* __restrict__ tot) {
  __shared__ float red[4][64];
  const int hd = blockIdx.x, seg = blockIdx.y;
  const int h = threadIdx.x & 63, sub = threadIdx.x >> 6;
  const bf16* Vh = Vp + (size_t)hd * S_ * H_;
  float a = 0.0f;
  const int k0 = seg * 32 + sub * 8;
#pragma unroll
  for (int k = 0; k < 8; ++k) a += (float)Vh[(size_t)(k0 + k) * H_ + h];
  red[sub][h] = a;
  __syncthreads();
  if (sub == 0)
    tot[(hd * 64 + seg) * 64 + h] = red[0][h] + red[1][h] + red[2][h] + red[3][h];
}

__global__ __launch_bounds__(64) void sufv_scan_kernel(
    bf16* __restrict__ VS, const float* __restrict__ tot) {
  const int hd = blockIdx.x, seg = blockIdx.y, h = threadIdx.x;
  bf16* Vh = VS + (size_t)hd * S_ * H_;  // in: V, out: Suf (in-place)
  float a = 0.0f;
  for (int s2 = seg + 1; s2 < 64; ++s2) a += tot[(hd * 64 + s2) * 64 + h];
  for (int k = seg * 32 + 31; k >= seg * 32; --k) {
    const float v = (float)Vh[(size_t)k * H_ + h];  // read BEFORE overwrite
    Vh[(size_t)k * H_ + h] = (bf16)a;
    a += v;
  }
}

// ---------------------------------------------------------------------------
// Merged QKV projection GEMM (swizzled LDS): A[4096x1024] bf16 x Wt[3072x1024].
// One dispatch, N=3072; 128-col blocks never straddle a z-boundary.
// grid (24, 32), block 256.
// ---------------------------------------------------------------------------
__global__ __launch_bounds__(256) void gemm_proj_kernel(
    const bf16* __restrict__ A, const bf16* __restrict__ Bt,
    const float* __restrict__ bk, const float* __restrict__ bq,
    const float* __restrict__ bv, bf16* __restrict__ proj_base) {
  __shared__ bf16 As[128 * 64];
  __shared__ bf16 Bs[128 * 64];
  const int tid = threadIdx.x;
  const int w = tid >> 6, l = tid & 63, lan = l & 15, grp = l >> 4;
  const int mb = (w >> 1) * 64, nb = (w & 1) * 64;
  const int m0 = blockIdx.y * 128, n0 = blockIdx.x * 128;
  const int zc = n0 >> 10;  // constant per block (1024 % 128 == 0)
  const float* bias = (zc == 0) ? bk : (zc == 1 ? bq : bv);
  bf16* Out = proj_base + (size_t)zc * ((size_t)B_ * N_ * S_ * H_);
  const int lrow8 = l >> 3;
  const int swl = ((l & 7) ^ lrow8) * 8;
  const int l7 = lan & 7;

  f32x4 acc[4][4];
#pragma unroll
  for (int i = 0; i < 4; ++i)
#pragma unroll
    for (int j = 0; j < 4; ++j) acc[i][j] = zero4();

  for (int kb = 0; kb < 1024; kb += 64) {
    __syncthreads();
#pragma unroll
    for (int i = 0; i < 4; ++i) {
      int ch = w * 4 + i;
      gload16(A + (size_t)(m0 + ch * 8 + lrow8) * 1024 + kb + swl, As + ch * 512);
      gload16(Bt + (size_t)(n0 + ch * 8 + lrow8) * 1024 + kb + swl, Bs + ch * 512);
    }
    __syncthreads();
#pragma unroll
    for (int kk = 0; kk < 2; ++kk) {
      bf16x8 a[4], b[4];
#pragma unroll
      for (int mf = 0; mf < 4; ++mf)
        a[mf] = *(const bf16x8*)(As + (mb + mf * 16 + lan) * 64 + (((grp + kk * 4) ^ l7) << 3));
#pragma unroll
      for (int nf = 0; nf < 4; ++nf)
        b[nf] = *(const bf16x8*)(Bs + (nb + nf * 16 + lan) * 64 + (((grp + kk * 4) ^ l7) << 3));
#pragma unroll
      for (int mf = 0; mf < 4; ++mf)
#pragma unroll
        for (int nf = 0; nf < 4; ++nf)
          acc[mf][nf] = mfma16(a[mf], b[nf], acc[mf][nf]);
    }
  }
#pragma unroll
  for (int nf = 0; nf < 4; ++nf) {
    int c10 = (n0 + nb + nf * 16 + lan) & 1023;
    float bs = bias[c10];
    int n = c10 >> 6, h = c10 & 63;
#pragma unroll
    for (int mf = 0; mf < 4; ++mf) {
#pragma unroll
      for (int r = 0; r < 4; ++r) {
        int m = m0 + mb + mf * 16 + grp * 4 + r;
        int b = m >> 11, s = m & 2047;
        Out[((size_t)((b * N_ + n) * S_ + s)) * H_ + h] = (bf16)(acc[mf][nf][r] + bs);
      }
    }
  }
}

// ---------------------------------------------------------------------------
// Output projection GEMM (swizzled LDS): weighted[4096x1024] x WoT -> fp32 out.
// ---------------------------------------------------------------------------
__global__ __launch_bounds__(256) void gemm_out_kernel(
    const bf16* __restrict__ A, const bf16* __restrict__ Bt,
    const float* __restrict__ bias, float* __restrict__ Out) {
  __shared__ bf16 As[128 * 64];
  __shared__ bf16 Bs[128 * 64];
  const int tid = threadIdx.x;
  const int w = tid >> 6, l = tid & 63, lan = l & 15, grp = l >> 4;
  const int mb = (w >> 1) * 64, nb = (w & 1) * 64;
  const int m0 = blockIdx.y * 128, n0 = blockIdx.x * 128;
  const int lrow8 = l >> 3;
  const int swl = ((l & 7) ^ lrow8) * 8;
  const int l7 = lan & 7;

  f32x4 acc[4][4];
#pragma unroll
  for (int i = 0; i < 4; ++i)
#pragma unroll
    for (int j = 0; j < 4; ++j) acc[i][j] = zero4();

  for (int kb = 0; kb < 1024; kb += 64) {
    __syncthreads();
#pragma unroll
    for (int i = 0; i < 4; ++i) {
      int ch = w * 4 + i;
      gload16(A + (size_t)(m0 + ch * 8 + lrow8) * 1024 + kb + swl, As + ch * 512);
      gload16(Bt + (size_t)(n0 + ch * 8 + lrow8) * 1024 + kb + swl, Bs + ch * 512);
    }
    __syncthreads();
#pragma unroll
    for (int kk = 0; kk < 2; ++kk) {
      bf16x8 a[4], b[4];
#pragma unroll
      for (int mf = 0; mf < 4; ++mf)
        a[mf] = *(const bf16x8*)(As + (mb + mf * 16 + lan) * 64 + (((grp + kk * 4) ^ l7) << 3));
#pragma unroll
      for (int nf = 0; nf < 4; ++nf)
        b[nf] = *(const bf16x8*)(Bs + (nb + nf * 16 + lan) * 64 + (((grp + kk * 4) ^ l7) << 3));
#pragma unroll
      for (int mf = 0; mf < 4; ++mf)
#pragma unroll
        for (int nf = 0; nf < 4; ++nf)
          acc[mf][nf] = mfma16(a[mf], b[nf], acc[mf][nf]);
    }
  }
#pragma unroll
  for (int nf = 0; nf < 4; ++nf) {
    int c = n0 + nb + nf * 16 + lan;
    float bs = bias[c];
#pragma unroll
    for (int mf = 0; mf < 4; ++mf) {
#pragma unroll
      for (int r = 0; r < 4; ++r) {
        int m = m0 + mb + mf * 16 + grp * 4 + r;
        Out[(size_t)m * 1024 + c] = acc[mf][nf][r] + bs;
      }
    }
  }
}

// ---------------------------------------------------------------------------
// Attention — EXACT R7 structure (measured 52 µs; R8/R9's psf/prescale
// variants measured 66 µs — reverted). Split-k, balanced:
//   quarter 0 (bi<256):  x=15-wv, k-tiles [0, x+1)     -> fp32 partial A
//   quarter 1 (bi<512):  x=15-wv, k-tiles [x+1, 2x+2)  -> fp32 partial B
//   quarter 2 (bi<768):  x=wv,    k-tiles [0, 2x+2)    -> final Wtd rows
// grid 768, block 256 (4 waves x 32 q-rows). Suf is bf16.
// ---------------------------------------------------------------------------
__global__ __launch_bounds__(256) void attn_kernel(
    const bf16* __restrict__ Qp, const bf16* __restrict__ Kp,
    const bf16* __restrict__ Vt, const bf16* __restrict__ Suf,
    bf16* __restrict__ Wtd, float* __restrict__ PoA, float* __restrict__ PoB,
    float* __restrict__ PpA, float* __restrict__ PpB) {
  __shared__ bf16 Ks[2][64 * 64];
  __shared__ bf16 Vs[2][64 * 64];
  __shared__ bf16 Ps[4][32 * 72];
  const int tid = threadIdx.x;
  const int w = tid >> 6, l = tid & 63, lan = l & 15, grp = l >> 4;
  const int bi = blockIdx.x;
  const int qq = bi >> 8;
  const int j = bi & 255;
  const int hd = j & 31, wv = j >> 5;
  int x, t0, t1;
  if (qq == 0)      { x = 15 - wv; t0 = 0;     t1 = x + 1; }
  else if (qq == 1) { x = 15 - wv; t0 = x + 1; t1 = 2 * x + 2; }
  else              { x = wv;      t0 = 0;     t1 = 2 * x + 2; }
  const int qw = x * 128 + w * 32;
  const bf16* Qh = Qp + (size_t)hd * S_ * H_;
  const bf16* Kh = Kp + (size_t)hd * S_ * H_;
  const bf16* Vh = Vt + (size_t)hd * H_ * S_;
  const bf16* Sufh = Suf + (size_t)hd * S_ * H_;
  const int lrow8 = l >> 3;
  const int swl = ((l & 7) ^ lrow8) * 8;
  const int l7 = lan & 7;
  const float cexp = 0.125f * LOG2E;

#define STAGE(buf, kb_)                                                        \
  do {                                                                         \
    _Pragma("unroll") for (int i2 = 0; i2 < 2; ++i2) {                         \
      int ch = w * 2 + i2;                                                     \
      gload16(Kh + (size_t)((kb_) + ch * 8 + lrow8) * H_ + swl,                \
              &Ks[buf][ch * 512]);                                             \
      gload16(Vh + (size_t)(ch * 8 + lrow8) * S_ + (kb_) + swl,                \
              &Vs[buf][ch * 512]);                                             \
    }                                                                          \
  } while (0)

  // Q fragments (B-operand for swapped QK^T: n=lan=q, k=grp*8+j (+32*kf))
  bf16x8 qa[2][2];
#pragma unroll
  for (int qt = 0; qt < 2; ++qt)
#pragma unroll
    for (int kf = 0; kf < 2; ++kf)
      qa[qt][kf] = *(const bf16x8*)(Qh + (size_t)(qw + qt * 16 + lan) * H_ + grp * 8 + kf * 32);

  f32x4 o[2][4];
  float psum[2] = {0.0f, 0.0f};
#pragma unroll
  for (int qt = 0; qt < 2; ++qt)
#pragma unroll
    for (int hf = 0; hf < 4; ++hf) o[qt][hf] = zero4();

  bf16* Pw = &Ps[w][0];

  STAGE(0, t0 * 64);
  for (int tt = t0; tt < t1; ++tt) {
    const int kb = tt * 64;
    const int cur = (tt - t0) & 1;
    if (tt + 1 < t1) {
      STAGE(cur ^ 1, kb + 64);
      asm volatile("s_waitcnt vmcnt(4)" ::: "memory");
    } else {
      asm volatile("s_waitcnt vmcnt(0)" ::: "memory");
    }
    __builtin_amdgcn_s_barrier();

    if (kb <= qw + 31) {
      const bf16* Kc = &Ks[cur][0];
      const bf16* Vc = &Vs[cur][0];

      // --- swapped QK^T: s2[k2][qt], col=lan=q, row=grp*4+r=k ---
      f32x4 s2[4][2];
#pragma unroll
      for (int k2 = 0; k2 < 4; ++k2)
#pragma unroll
        for (int qt = 0; qt < 2; ++qt) s2[k2][qt] = zero4();
      __builtin_amdgcn_s_setprio(1);
#pragma unroll
      for (int kf = 0; kf < 2; ++kf) {
        bf16x8 kfr[4];
#pragma unroll
        for (int k2 = 0; k2 < 4; ++k2)
          kfr[k2] = *(const bf16x8*)(Kc + (k2 * 16 + lan) * 64 + (((grp + kf * 4) ^ l7) << 3));
#pragma unroll
        for (int k2 = 0; k2 < 4; ++k2)
#pragma unroll
          for (int qt = 0; qt < 2; ++qt)
            s2[k2][qt] = mfma16(kfr[k2], qa[qt][kf], s2[k2][qt]);
      }
      __builtin_amdgcn_s_setprio(0);

      // --- exp, diag-mask, psum, pack two cvt_pk -> one b64 write ---
      const bool maskt = (kb + 63 > qw);
#pragma unroll
      for (int qt = 0; qt < 2; ++qt) {
        const int q_g = qw + qt * 16 + lan;
#pragma unroll
        for (int k2 = 0; k2 < 4; ++k2) {
          f32x4 p;
#pragma unroll
          for (int r = 0; r < 4; ++r) p[r] = exp2f(s2[k2][qt][r] * cexp);
          if (maskt) {
            const int kg0 = kb + k2 * 16 + grp * 4;
#pragma unroll
            for (int r = 0; r < 4; ++r)
              if (kg0 + r > q_g) p[r] = 0.0f;
          }
          psum[qt] += (p[0] + p[1]) + (p[2] + p[3]);
          unsigned plo, phi;
          asm("v_cvt_pk_bf16_f32 %0, %1, %2" : "=v"(plo) : "v"(p[0]), "v"(p[1]));
          asm("v_cvt_pk_bf16_f32 %0, %1, %2" : "=v"(phi) : "v"(p[2]), "v"(p[3]));
          uint2 u; u.x = plo; u.y = phi;
          *(uint2*)(Pw + (qt * 16 + lan) * 72 + k2 * 16 + grp * 4) = u;
        }
      }

      // --- PV ---
      __builtin_amdgcn_s_setprio(1);
#pragma unroll
      for (int ks = 0; ks < 2; ++ks) {
        bf16x8 pa[2], vb[4];
#pragma unroll
        for (int qt = 0; qt < 2; ++qt)
          pa[qt] = *(const bf16x8*)(Pw + (qt * 16 + lan) * 72 + grp * 8 + ks * 32);
#pragma unroll
        for (int hf = 0; hf < 4; ++hf)
          vb[hf] = *(const bf16x8*)(Vc + (hf * 16 + lan) * 64 + (((grp + ks * 4) ^ l7) << 3));
#pragma unroll
        for (int qt = 0; qt < 2; ++qt)
#pragma unroll
          for (int hf = 0; hf < 4; ++hf)
            o[qt][hf] = mfma16(pa[qt], vb[hf], o[qt][hf]);
      }
      __builtin_amdgcn_s_setprio(0);
    }
    __builtin_amdgcn_s_barrier();
  }
#undef STAGE

  // psum: reduce over grp (lanes sharing lan); q = qt*16+lan
#pragma unroll
  for (int qt = 0; qt < 2; ++qt) {
    psum[qt] += __shfl_xor(psum[qt], 16);
    psum[qt] += __shfl_xor(psum[qt], 32);
  }

  if (qq == 2) {
    // final: o = (o_causal + SufV) / (psum + (2047-q))
    const size_t outbase = (size_t)(hd >> 4) * S_ * (N_ * H_) + (size_t)(hd & 15) * H_;
#pragma unroll
    for (int qt = 0; qt < 2; ++qt) {
#pragma unroll
      for (int r = 0; r < 4; ++r) {
        const int q_g = qw + qt * 16 + grp * 4 + r;
        const float ps = __shfl(psum[qt], grp * 4 + r);
        const float inv = 1.0f / (ps + (float)(2047 - q_g));
#pragma unroll
        for (int hf = 0; hf < 4; ++hf) {
          const int h = hf * 16 + lan;
          const float suf = (float)Sufh[(size_t)q_g * H_ + h];
          Wtd[outbase + (size_t)q_g * (N_ * H_) + h] = (bf16)((o[qt][hf][r] + suf) * inv);
        }
      }
    }
  } else {
    // partial: raw fp32 o + row psums
    float* Po = (qq == 0) ? PoA : PoB;
    float* Pp = (qq == 0) ? PpA : PpB;
    const int pb = (hd * 8 + (x - 8)) * 128 + w * 32;
#pragma unroll
    for (int qt = 0; qt < 2; ++qt) {
#pragma unroll
      for (int r = 0; r < 4; ++r) {
        const int rl = qt * 16 + grp * 4 + r;
        const float ps = __shfl(psum[qt], grp * 4 + r);
        if (lan == 0) Pp[pb + rl] = ps;
#pragma unroll
        for (int hf = 0; hf < 4; ++hf)
          Po[(size_t)(pb + rl) * 64 + hf * 16 + lan] = o[qt][hf][r];
      }
    }
  }
}

// ---------------------------------------------------------------------------
// Combine: for x in 8..15, Wtd = (PoA + PoB + Suf) / (PpA + PpB + 2047-q).
// ---------------------------------------------------------------------------
__global__ __launch_bounds__(256) void combine_kernel(
    const float* __restrict__ PoA, const float* __restrict__ PoB,
    const float* __restrict__ PpA, const float* __restrict__ PpB,
    const bf16* __restrict__ Suf, bf16* __restrict__ Wtd) {
  const int hd = blockIdx.x >> 3, xi = blockIdx.x & 7;
  const int x = xi + 8;
  const int pb = (hd * 8 + xi) * 128;
  const size_t outbase = (size_t)(hd >> 4) * S_ * (N_ * H_) + (size_t)(hd & 15) * H_;
#pragma unroll
  for (int it = 0; it < 8; ++it) {
    const int e = it * 256 + threadIdx.x;  // 0..2047 float4 units
    const int rl = e >> 4, h4 = (e & 15) * 4;
    const int q_g = x * 128 + rl;
    const float Z = PpA[pb + rl] + PpB[pb + rl] + (float)(2047 - q_g);
    const float inv = 1.0f / Z;
    const float4 a = *(const float4*)(PoA + (size_t)(pb + rl) * 64 + h4);
    const float4 b = *(const float4*)(PoB + (size_t)(pb + rl) * 64 + h4);
    const bf16x4 s4 = *(const bf16x4*)(Suf + ((size_t)hd * S_ + q_g) * 64 + h4);
    bf16x4 ov;
    ov[0] = (bf16)((a.x + b.x + (float)s4[0]) * inv);
    ov[1] = (bf16)((a.y + b.y + (float)s4[1]) * inv);
    ov[2] = (bf16)((a.z + b.z + (float)s4[2]) * inv);
    ov[3] = (bf16)((a.w + b.w + (float)s4[3]) * inv);
    *(bf16x4*)(Wtd + outbase + (size_t)q_g * (N_ * H_) + h4) = ov;
  }
}

// ---------------------------------------------------------------------------
extern "C" void kernel_launch(void* const* d_in, const int* in_sizes, int n_in,
                              void* d_out, int out_size, void* d_ws, size_t ws_size,
                              hipStream_t stream) {
  const float* residual = (const float*)d_in[0];
  const float* Wk = (const float*)d_in[1];
  const float* Wq = (const float*)d_in[2];
  const float* Wv = (const float*)d_in[3];
  const float* Wo = (const float*)d_in[4];
  const float* Bk = (const float*)d_in[5];
  const float* Bq = (const float*)d_in[6];
  const float* Bv = (const float*)d_in[7];
  const float* Bo = (const float*)d_in[8];
  float* outp = (float*)d_out;

  // ws layout (peak 48MB — proven safe; do NOT exceed):
  //   [ 0.. 8) Abf (cvt out, gemm_proj A)        -> Wtd (attn/combine out)
  //   [ 8..10) Wot (live to end)
  //   [10..16) Wkt (gemm_proj B, [3072][1024])   -> PpA, PpB, tot
  //   [16..24) Kp   [24..32) Qp
  //   [32..40) Vp (proj V) -> in-place Suf (bf16) via sufv_scan
  //   [40..48) Vtp
  // d_out (16MB fp32): PoA [0..8MB) + PoB [8..16MB) until gemm_out overwrites.
  char* ws = (char*)d_ws;
  const size_t MB = 1024 * 1024;
  bf16* Abf = (bf16*)(ws + 0 * MB);
  bf16* Wot = (bf16*)(ws + 8 * MB);
  bf16* Wkt = (bf16*)(ws + 10 * MB);
  bf16* Kp  = (bf16*)(ws + 16 * MB);
  bf16* Qp  = (bf16*)(ws + 24 * MB);
  bf16* Vp  = (bf16*)(ws + 32 * MB);
  bf16* Vtp = (bf16*)(ws + 40 * MB);
  bf16* Wtd = Abf;                                   // dead after gemm_proj
  float* PpA = (float*)(ws + 10 * MB);               // [32][8][128] (128KB)
  float* PpB = (float*)(ws + 10 * MB + 128 * 1024);  // (128KB)
  float* tot = (float*)(ws + 10 * MB + 256 * 1024);  // [32][64][64] (512KB)
  bf16* Suf = Vp;                                    // in-place over Vp
  float* PoA = (float*)d_out;                        // [32][8][128][64] (8MB)
  float* PoB = (float*)d_out + 2 * 1024 * 1024;      // (8MB)
  (void)in_sizes; (void)n_in; (void)out_size; (void)ws_size;

  // residual fp32 -> bf16
  cvt_kernel<<<2048, 256, 0, stream>>>(residual, Abf, (B_ * S_ * D_) / 8);

  // weight transposes
  qkvw_transpose_kernel<<<dim3(16, 1, 48), 256, 0, stream>>>(Wk, Wq, Wv, Wkt);
  transpose_f32bf16_kernel<<<dim3(16, 16, 1), 256, 0, stream>>>(Wo, Wot, 1024, 1024);

  // QKV projections — single merged dispatch, N=3072
  gemm_proj_kernel<<<dim3(24, 32), 256, 0, stream>>>(Abf, Wkt, Bk, Bq, Bv, Kp);

  // V consumers BEFORE the in-place suffix scan:
  sufv_tot_kernel<<<dim3(32, 64), 256, 0, stream>>>(Vp, tot);
  transpose_bf16_kernel<<<dim3(32, 1, 32), 256, 0, stream>>>(Vp, Vtp, 2048, 64);
  // in-place: Vp becomes Suf (bf16)
  sufv_scan_kernel<<<dim3(32, 64), 64, 0, stream>>>(Vp, tot);

  // attention: split-k, balanced (34 tiles per CU triple)
  attn_kernel<<<768, 256, 0, stream>>>(Qp, Kp, Vtp, Suf, Wtd, PoA, PoB, PpA, PpB);

  // combine halves for x >= 8
  combine_kernel<<<256, 256, 0, stream>>>(PoA, PoB, PpA, PpB, Suf, Wtd);

  // output projection -> fp32 d_out (overwrites PoA/PoB scratch)
  gemm_out_kernel<<<dim3(8, 32, 1), 256, 0, stream>>>(Wtd, Wot, Bo, outp);
}

// Round 11
// 149.001 us; speedup vs baseline: 1.1529x; 1.0415x over previous
//
#include <hip/hip_runtime.h>
#include <hip/hip_bf16.h>
#include <cmath>

typedef __bf16 bf16;
typedef __attribute__((ext_vector_type(4))) __bf16 bf16x4;
typedef __attribute__((ext_vector_type(8))) __bf16 bf16x8;
typedef __attribute__((ext_vector_type(4))) float f32x4;

#define B_ 2
#define S_ 2048
#define D_ 1024
#define N_ 16
#define H_ 64
#define LOG2E 1.44269504088896340736f

__device__ __forceinline__ void gload16(const bf16* g, bf16* l) {
  __builtin_amdgcn_global_load_lds(
      (const __attribute__((address_space(1))) void*)(g),
      (__attribute__((address_space(3))) void*)(l), 16, 0, 0);
}

__device__ __forceinline__ f32x4 mfma16(bf16x8 a, bf16x8 b, f32x4 c) {
  return __builtin_amdgcn_mfma_f32_16x16x32_bf16(a, b, c, 0, 0, 0);
}

__device__ __forceinline__ f32x4 zero4() {
  f32x4 v = {0.0f, 0.0f, 0.0f, 0.0f};
  return v;
}

// ---------------------------------------------------------------------------
// fp32 -> bf16 elementwise convert. 8 elems/thread.
// ---------------------------------------------------------------------------
__global__ __launch_bounds__(256) void cvt_kernel(
    const float* __restrict__ in, bf16* __restrict__ out, int n8) {
  int id = blockIdx.x * 256 + threadIdx.x;
  if (id >= n8) return;
  const float4* p = (const float4*)(in + (size_t)id * 8);
  float4 v0 = p[0], v1 = p[1];
  bf16x8 o;
  o[0] = (bf16)v0.x; o[1] = (bf16)v0.y; o[2] = (bf16)v0.z; o[3] = (bf16)v0.w;
  o[4] = (bf16)v1.x; o[5] = (bf16)v1.y; o[6] = (bf16)v1.z; o[7] = (bf16)v1.w;
  *(bf16x8*)(out + (size_t)id * 8) = o;
}

// ---------------------------------------------------------------------------
// Merged QKV weight transpose: head z (0..47) of {Wk,Wq,Wv}, [1024][64] fp32
// -> [64][1024] bf16 at out + z*64*1024. grid (16, 1, 48), block 256.
// ---------------------------------------------------------------------------
__global__ __launch_bounds__(256) void qkvw_transpose_kernel(
    const float* __restrict__ Wk, const float* __restrict__ Wq,
    const float* __restrict__ Wv, bf16* __restrict__ out) {
  __shared__ bf16 t[64][72];
  const int z = blockIdx.z;
  const float* W = (z < 16) ? Wk : (z < 32) ? Wq : Wv;
  const float* ing = W + (size_t)(z & 15) * (1024 * 64);
  bf16* outg = out + (size_t)z * (64 * 1024);
  const int r0 = blockIdx.x * 64;
  const int t8 = threadIdx.x & 7, trow = threadIdx.x >> 3;
#pragma unroll
  for (int p = 0; p < 2; ++p) {
    int r = trow + p * 32;
    const float4* src = (const float4*)(ing + (size_t)(r0 + r) * 64 + t8 * 8);
    float4 v0 = src[0], v1 = src[1];
    bf16x8 o;
    o[0] = (bf16)v0.x; o[1] = (bf16)v0.y; o[2] = (bf16)v0.z; o[3] = (bf16)v0.w;
    o[4] = (bf16)v1.x; o[5] = (bf16)v1.y; o[6] = (bf16)v1.z; o[7] = (bf16)v1.w;
    *(bf16x8*)(&t[r][t8 * 8]) = o;
  }
  __syncthreads();
#pragma unroll
  for (int p = 0; p < 2; ++p) {
    int c = trow + p * 32;
    bf16x8 v;
#pragma unroll
    for (int j = 0; j < 8; ++j) v[j] = t[t8 * 8 + j][c];
    *(bf16x8*)(outg + (size_t)c * 1024 + r0 + t8 * 8) = v;
  }
}

// ---------------------------------------------------------------------------
// Transpose fp32 [R][C] -> bf16 [C][R], G matrices. grid (R/64, C/64, G), 256.
// ---------------------------------------------------------------------------
__global__ __launch_bounds__(256) void transpose_f32bf16_kernel(
    const float* __restrict__ in, bf16* __restrict__ out, int R, int C) {
  __shared__ bf16 t[64][72];
  const size_t mat = (size_t)R * C;
  const float* ing = in + (size_t)blockIdx.z * mat;
  bf16* outg = out + (size_t)blockIdx.z * mat;
  const int r0 = blockIdx.x * 64, c0 = blockIdx.y * 64;
  const int t8 = threadIdx.x & 7, trow = threadIdx.x >> 3;
#pragma unroll
  for (int p = 0; p < 2; ++p) {
    int r = trow + p * 32;
    const float4* src = (const float4*)(ing + (size_t)(r0 + r) * C + c0 + t8 * 8);
    float4 v0 = src[0], v1 = src[1];
    bf16x8 o;
    o[0] = (bf16)v0.x; o[1] = (bf16)v0.y; o[2] = (bf16)v0.z; o[3] = (bf16)v0.w;
    o[4] = (bf16)v1.x; o[5] = (bf16)v1.y; o[6] = (bf16)v1.z; o[7] = (bf16)v1.w;
    *(bf16x8*)(&t[r][t8 * 8]) = o;
  }
  __syncthreads();
#pragma unroll
  for (int p = 0; p < 2; ++p) {
    int c = trow + p * 32;
    bf16x8 v;
#pragma unroll
    for (int j = 0; j < 8; ++j) v[j] = t[t8 * 8 + j][c];
    *(bf16x8*)(outg + (size_t)(c0 + c) * R + r0 + t8 * 8) = v;
  }
}

// ---------------------------------------------------------------------------
// Transpose bf16 [R][C] -> bf16 [C][R], G matrices.
// ---------------------------------------------------------------------------
__global__ __launch_bounds__(256) void transpose_bf16_kernel(
    const bf16* __restrict__ in, bf16* __restrict__ out, int R, int C) {
  __shared__ bf16 t[64][72];
  const size_t mat = (size_t)R * C;
  const bf16* ing = in + (size_t)blockIdx.z * mat;
  bf16* outg = out + (size_t)blockIdx.z * mat;
  const int r0 = blockIdx.x * 64, c0 = blockIdx.y * 64;
  const int t8 = threadIdx.x & 7, trow = threadIdx.x >> 3;
#pragma unroll
  for (int p = 0; p < 2; ++p) {
    int r = trow + p * 32;
    bf16x8 v = *(const bf16x8*)(ing + (size_t)(r0 + r) * C + c0 + t8 * 8);
    *(bf16x8*)(&t[r][t8 * 8]) = v;
  }
  __syncthreads();
#pragma unroll
  for (int p = 0; p < 2; ++p) {
    int c = trow + p * 32;
    bf16x8 v;
#pragma unroll
    for (int j = 0; j < 8; ++j) v[j] = t[t8 * 8 + j][c];
    *(bf16x8*)(outg + (size_t)(c0 + c) * R + r0 + t8 * 8) = v;
  }
}

// ---------------------------------------------------------------------------
// Suffix-V (32-row segments): Suf[hd][q][h] = sum_{k>q} V[hd][k][h].
// Suf is bf16, computed IN-PLACE over Vp (strict read-element-then-write).
// ---------------------------------------------------------------------------
__global__ __launch_bounds__(256) void sufv_tot_kernel(
    const bf16* __restrict__ Vp, float* __restrict__ tot) {
  __shared__ float red[4][64];
  const int hd = blockIdx.x, seg = blockIdx.y;
  const int h = threadIdx.x & 63, sub = threadIdx.x >> 6;
  const bf16* Vh = Vp + (size_t)hd * S_ * H_;
  float a = 0.0f;
  const int k0 = seg * 32 + sub * 8;
#pragma unroll
  for (int k = 0; k < 8; ++k) a += (float)Vh[(size_t)(k0 + k) * H_ + h];
  red[sub][h] = a;
  __syncthreads();
  if (sub == 0)
    tot[(hd * 64 + seg) * 64 + h] = red[0][h] + red[1][h] + red[2][h] + red[3][h];
}

__global__ __launch_bounds__(64) void sufv_scan_kernel(
    bf16* __restrict__ VS, const float* __restrict__ tot) {
  const int hd = blockIdx.x, seg = blockIdx.y, h = threadIdx.x;
  bf16* Vh = VS + (size_t)hd * S_ * H_;  // in: V, out: Suf (in-place)
  float a = 0.0f;
  for (int s2 = seg + 1; s2 < 64; ++s2) a += tot[(hd * 64 + s2) * 64 + h];
  for (int k = seg * 32 + 31; k >= seg * 32; --k) {
    const float v = (float)Vh[(size_t)k * H_ + h];  // read BEFORE overwrite
    Vh[(size_t)k * H_ + h] = (bf16)a;
    a += v;
  }
}

// ---------------------------------------------------------------------------
// QKV projection GEMM v2: 256x256 tile, BK=64, 512 threads (8 waves 2Mx4N),
// 4 phases/K-step {STAGE(next slot) -> counted vmcnt -> barrier -> ds_read ->
// 16 MFMA} (T3/T4; R7-skeleton at phase granularity). LDS = 4-slot half-tile
// ring per operand ([dbuf][khalf][256][32]) = 128KB, 1 block/CU.
// Conflict-free via pre-swizzled source: chunk ^= (row>>1)&3 (both sides).
// A[4096x1024] x Wt[3072x1024]^T -> proj[z][B][N][S][H]. grid (12,16), 512.
// ---------------------------------------------------------------------------
__global__ __launch_bounds__(512) void gemm_proj_kernel(
    const bf16* __restrict__ A, const bf16* __restrict__ Bt,
    const float* __restrict__ bk, const float* __restrict__ bq,
    const float* __restrict__ bv, bf16* __restrict__ proj_base) {
  __shared__ bf16 As[2][2][256 * 32];
  __shared__ bf16 Bs[2][2][256 * 32];
  const int tid = threadIdx.x;
  const int w = tid >> 6, l = tid & 63, lan = l & 15, grp = l >> 4;
  const int wm128 = (w >> 2) * 128, wn64 = (w & 3) * 64;
  const int m0 = blockIdx.y * 256, n0 = blockIdx.x * 256;
  const int zc = n0 >> 10;  // block-uniform (1024 % 256 == 0)
  const float* bias = (zc == 0) ? bk : (zc == 1 ? bq : bv);
  bf16* Out = proj_base + (size_t)zc * ((size_t)B_ * N_ * S_ * H_);
  const int posx = (grp ^ ((lan >> 1) & 3)) << 3;  // swizzled read chunk

  // stage one half-tile (256 rows x 32 k): 2 gload16/thread, linear LDS dest
  // (wave-uniform base + lane*16B), pre-swizzled global chunk (G21).
#define STG(LDS_, GP_, rb_, buf_, kh_, kb_)                                    \
  do {                                                                         \
    _Pragma("unroll") for (int jj = 0; jj < 2; ++jj) {                         \
      const int ci = jj * 512 + tid;                                           \
      const int rw = ci >> 2, cp = ci & 3;                                     \
      const int gg = cp ^ ((rw >> 1) & 3);                                     \
      gload16(GP_ + (size_t)((rb_) + rw) * 1024 + (kb_) + (kh_) * 32 + gg * 8, \
              &LDS_[buf_][kh_][(jj * 512 + w * 64) * 8]);                      \
    }                                                                          \
  } while (0)

  f32x4 acc[8][4];
#pragma unroll
  for (int i = 0; i < 8; ++i)
#pragma unroll
    for (int jv = 0; jv < 4; ++jv) acc[i][jv] = zero4();

  bf16x8 b[4];

#define DO_PHASE(buf_, mq_, kk_, READB_)                                       \
  do {                                                                         \
    if (READB_) {                                                              \
      _Pragma("unroll") for (int nf = 0; nf < 4; ++nf)                         \
        b[nf] = *(const bf16x8*)(&Bs[buf_][kk_][(wn64 + nf * 16 + lan) * 32 + posx]); \
    }                                                                          \
    bf16x8 a[4];                                                               \
    _Pragma("unroll") for (int mf = 0; mf < 4; ++mf)                           \
      a[mf] = *(const bf16x8*)(&As[buf_][kk_][(wm128 + (mq_) * 64 + mf * 16 + lan) * 32 + posx]); \
    __builtin_amdgcn_s_setprio(1);                                             \
    _Pragma("unroll") for (int mf = 0; mf < 4; ++mf)                           \
      _Pragma("unroll") for (int nf = 0; nf < 4; ++nf)                         \
        acc[(mq_) * 4 + mf][nf] = mfma16(a[mf], b[nf], acc[(mq_) * 4 + mf][nf]); \
    __builtin_amdgcn_s_setprio(0);                                             \
  } while (0)

  // prologue: all 4 slots of K-step 0 into buf 0 (order: A0,B0,A1,B1)
  STG(As, A, m0, 0, 0, 0);
  STG(Bs, Bt, n0, 0, 0, 0);
  STG(As, A, m0, 0, 1, 0);
  STG(Bs, Bt, n0, 0, 1, 0);

  for (int t = 0; t < 15; ++t) {
    const int buf = t & 1;
    const int nkb = (t + 1) * 64;
    // q0: consume (kh0); prefetch A-kh0 of t+1
    STG(As, A, m0, buf ^ 1, 0, nkb);
    asm volatile("s_waitcnt vmcnt(6)" ::: "memory");
    __builtin_amdgcn_s_barrier();
    asm volatile("" ::: "memory");
    DO_PHASE(buf, 0, 0, true);
    // q1
    STG(Bs, Bt, n0, buf ^ 1, 0, nkb);
    asm volatile("" ::: "memory");
    __builtin_amdgcn_s_barrier();
    asm volatile("" ::: "memory");
    DO_PHASE(buf, 1, 0, false);
    // q2: consume (kh1); prefetch A-kh1 of t+1
    STG(As, A, m0, buf ^ 1, 1, nkb);
    asm volatile("s_waitcnt vmcnt(6)" ::: "memory");
    __builtin_amdgcn_s_barrier();
    asm volatile("" ::: "memory");
    DO_PHASE(buf, 0, 1, true);
    // q3
    STG(Bs, Bt, n0, buf ^ 1, 1, nkb);
    asm volatile("" ::: "memory");
    __builtin_amdgcn_s_barrier();
    asm volatile("" ::: "memory");
    DO_PHASE(buf, 1, 1, false);
  }
  // peeled t = 15 (no prefetch): vmcnt 4 then 0
  {
    asm volatile("s_waitcnt vmcnt(4)" ::: "memory");
    __builtin_amdgcn_s_barrier();
    asm volatile("" ::: "memory");
    DO_PHASE(1, 0, 0, true);
    DO_PHASE(1, 1, 0, false);
    asm volatile("s_waitcnt vmcnt(0)" ::: "memory");
    __builtin_amdgcn_s_barrier();
    asm volatile("" ::: "memory");
    DO_PHASE(1, 0, 1, true);
    DO_PHASE(1, 1, 1, false);
  }
#undef STG
#undef DO_PHASE

  // epilogue: scatter to [z][b][n][s][h] + bias
#pragma unroll
  for (int nf = 0; nf < 4; ++nf) {
    const int c10 = (n0 + wn64 + nf * 16 + lan) & 1023;
    const float bs = bias[c10];
    const int n = c10 >> 6, h = c10 & 63;
#pragma unroll
    for (int am = 0; am < 8; ++am) {
#pragma unroll
      for (int r = 0; r < 4; ++r) {
        const int m = m0 + wm128 + am * 16 + grp * 4 + r;
        const int bb = m >> 11, s = m & 2047;
        Out[((size_t)((bb * N_ + n) * S_ + s)) * H_ + h] = (bf16)(acc[am][nf][r] + bs);
      }
    }
  }
}

// ---------------------------------------------------------------------------
// Output projection GEMM (swizzled LDS): weighted[4096x1024] x WoT -> fp32 out.
// ---------------------------------------------------------------------------
__global__ __launch_bounds__(256) void gemm_out_kernel(
    const bf16* __restrict__ A, const bf16* __restrict__ Bt,
    const float* __restrict__ bias, float* __restrict__ Out) {
  __shared__ bf16 As[128 * 64];
  __shared__ bf16 Bs[128 * 64];
  const int tid = threadIdx.x;
  const int w = tid >> 6, l = tid & 63, lan = l & 15, grp = l >> 4;
  const int mb = (w >> 1) * 64, nb = (w & 1) * 64;
  const int m0 = blockIdx.y * 128, n0 = blockIdx.x * 128;
  const int lrow8 = l >> 3;
  const int swl = ((l & 7) ^ lrow8) * 8;
  const int l7 = lan & 7;

  f32x4 acc[4][4];
#pragma unroll
  for (int i = 0; i < 4; ++i)
#pragma unroll
    for (int j = 0; j < 4; ++j) acc[i][j] = zero4();

  for (int kb = 0; kb < 1024; kb += 64) {
    __syncthreads();
#pragma unroll
    for (int i = 0; i < 4; ++i) {
      int ch = w * 4 + i;
      gload16(A + (size_t)(m0 + ch * 8 + lrow8) * 1024 + kb + swl, As + ch * 512);
      gload16(Bt + (size_t)(n0 + ch * 8 + lrow8) * 1024 + kb + swl, Bs + ch * 512);
    }
    __syncthreads();
#pragma unroll
    for (int kk = 0; kk < 2; ++kk) {
      bf16x8 a[4], b[4];
#pragma unroll
      for (int mf = 0; mf < 4; ++mf)
        a[mf] = *(const bf16x8*)(As + (mb + mf * 16 + lan) * 64 + (((grp + kk * 4) ^ l7) << 3));
#pragma unroll
      for (int nf = 0; nf < 4; ++nf)
        b[nf] = *(const bf16x8*)(Bs + (nb + nf * 16 + lan) * 64 + (((grp + kk * 4) ^ l7) << 3));
#pragma unroll
      for (int mf = 0; mf < 4; ++mf)
#pragma unroll
        for (int nf = 0; nf < 4; ++nf)
          acc[mf][nf] = mfma16(a[mf], b[nf], acc[mf][nf]);
    }
  }
#pragma unroll
  for (int nf = 0; nf < 4; ++nf) {
    int c = n0 + nb + nf * 16 + lan;
    float bs = bias[c];
#pragma unroll
    for (int mf = 0; mf < 4; ++mf) {
#pragma unroll
      for (int r = 0; r < 4; ++r) {
        int m = m0 + mb + mf * 16 + grp * 4 + r;
        Out[(size_t)m * 1024 + c] = acc[mf][nf][r] + bs;
      }
    }
  }
}

// ---------------------------------------------------------------------------
// Attention — EXACT R7 structure (measured 52 µs). Split-k, balanced:
//   quarter 0 (bi<256):  x=15-wv, k-tiles [0, x+1)     -> fp32 partial A
//   quarter 1 (bi<512):  x=15-wv, k-tiles [x+1, 2x+2)  -> fp32 partial B
//   quarter 2 (bi<768):  x=wv,    k-tiles [0, 2x+2)    -> final Wtd rows
// grid 768, block 256 (4 waves x 32 q-rows). Suf is bf16.
// ---------------------------------------------------------------------------
__global__ __launch_bounds__(256) void attn_kernel(
    const bf16* __restrict__ Qp, const bf16* __restrict__ Kp,
    const bf16* __restrict__ Vt, const bf16* __restrict__ Suf,
    bf16* __restrict__ Wtd, float* __restrict__ PoA, float* __restrict__ PoB,
    float* __restrict__ PpA, float* __restrict__ PpB) {
  __shared__ bf16 Ks[2][64 * 64];
  __shared__ bf16 Vs[2][64 * 64];
  __shared__ bf16 Ps[4][32 * 72];
  const int tid = threadIdx.x;
  const int w = tid >> 6, l = tid & 63, lan = l & 15, grp = l >> 4;
  const int bi = blockIdx.x;
  const int qq = bi >> 8;
  const int j = bi & 255;
  const int hd = j & 31, wv = j >> 5;
  int x, t0, t1;
  if (qq == 0)      { x = 15 - wv; t0 = 0;     t1 = x + 1; }
  else if (qq == 1) { x = 15 - wv; t0 = x + 1; t1 = 2 * x + 2; }
  else              { x = wv;      t0 = 0;     t1 = 2 * x + 2; }
  const int qw = x * 128 + w * 32;
  const bf16* Qh = Qp + (size_t)hd * S_ * H_;
  const bf16* Kh = Kp + (size_t)hd * S_ * H_;
  const bf16* Vh = Vt + (size_t)hd * H_ * S_;
  const bf16* Sufh = Suf + (size_t)hd * S_ * H_;
  const int lrow8 = l >> 3;
  const int swl = ((l & 7) ^ lrow8) * 8;
  const int l7 = lan & 7;
  const float cexp = 0.125f * LOG2E;

#define STAGE(buf, kb_)                                                        \
  do {                                                                         \
    _Pragma("unroll") for (int i2 = 0; i2 < 2; ++i2) {                         \
      int ch = w * 2 + i2;                                                     \
      gload16(Kh + (size_t)((kb_) + ch * 8 + lrow8) * H_ + swl,                \
              &Ks[buf][ch * 512]);                                             \
      gload16(Vh + (size_t)(ch * 8 + lrow8) * S_ + (kb_) + swl,                \
              &Vs[buf][ch * 512]);                                             \
    }                                                                          \
  } while (0)

  // Q fragments (B-operand for swapped QK^T: n=lan=q, k=grp*8+j (+32*kf))
  bf16x8 qa[2][2];
#pragma unroll
  for (int qt = 0; qt < 2; ++qt)
#pragma unroll
    for (int kf = 0; kf < 2; ++kf)
      qa[qt][kf] = *(const bf16x8*)(Qh + (size_t)(qw + qt * 16 + lan) * H_ + grp * 8 + kf * 32);

  f32x4 o[2][4];
  float psum[2] = {0.0f, 0.0f};
#pragma unroll
  for (int qt = 0; qt < 2; ++qt)
#pragma unroll
    for (int hf = 0; hf < 4; ++hf) o[qt][hf] = zero4();

  bf16* Pw = &Ps[w][0];

  STAGE(0, t0 * 64);
  for (int tt = t0; tt < t1; ++tt) {
    const int kb = tt * 64;
    const int cur = (tt - t0) & 1;
    if (tt + 1 < t1) {
      STAGE(cur ^ 1, kb + 64);
      asm volatile("s_waitcnt vmcnt(4)" ::: "memory");
    } else {
      asm volatile("s_waitcnt vmcnt(0)" ::: "memory");
    }
    __builtin_amdgcn_s_barrier();

    if (kb <= qw + 31) {
      const bf16* Kc = &Ks[cur][0];
      const bf16* Vc = &Vs[cur][0];

      // --- swapped QK^T: s2[k2][qt], col=lan=q, row=grp*4+r=k ---
      f32x4 s2[4][2];
#pragma unroll
      for (int k2 = 0; k2 < 4; ++k2)
#pragma unroll
        for (int qt = 0; qt < 2; ++qt) s2[k2][qt] = zero4();
      __builtin_amdgcn_s_setprio(1);
#pragma unroll
      for (int kf = 0; kf < 2; ++kf) {
        bf16x8 kfr[4];
#pragma unroll
        for (int k2 = 0; k2 < 4; ++k2)
          kfr[k2] = *(const bf16x8*)(Kc + (k2 * 16 + lan) * 64 + (((grp + kf * 4) ^ l7) << 3));
#pragma unroll
        for (int k2 = 0; k2 < 4; ++k2)
#pragma unroll
          for (int qt = 0; qt < 2; ++qt)
            s2[k2][qt] = mfma16(kfr[k2], qa[qt][kf], s2[k2][qt]);
      }
      __builtin_amdgcn_s_setprio(0);

      // --- exp, diag-mask, psum, pack two cvt_pk -> one b64 write ---
      const bool maskt = (kb + 63 > qw);
#pragma unroll
      for (int qt = 0; qt < 2; ++qt) {
        const int q_g = qw + qt * 16 + lan;
#pragma unroll
        for (int k2 = 0; k2 < 4; ++k2) {
          f32x4 p;
#pragma unroll
          for (int r = 0; r < 4; ++r) p[r] = exp2f(s2[k2][qt][r] * cexp);
          if (maskt) {
            const int kg0 = kb + k2 * 16 + grp * 4;
#pragma unroll
            for (int r = 0; r < 4; ++r)
              if (kg0 + r > q_g) p[r] = 0.0f;
          }
          psum[qt] += (p[0] + p[1]) + (p[2] + p[3]);
          unsigned plo, phi;
          asm("v_cvt_pk_bf16_f32 %0, %1, %2" : "=v"(plo) : "v"(p[0]), "v"(p[1]));
          asm("v_cvt_pk_bf16_f32 %0, %1, %2" : "=v"(phi) : "v"(p[2]), "v"(p[3]));
          uint2 u; u.x = plo; u.y = phi;
          *(uint2*)(Pw + (qt * 16 + lan) * 72 + k2 * 16 + grp * 4) = u;
        }
      }

      // --- PV ---
      __builtin_amdgcn_s_setprio(1);
#pragma unroll
      for (int ks = 0; ks < 2; ++ks) {
        bf16x8 pa[2], vb[4];
#pragma unroll
        for (int qt = 0; qt < 2; ++qt)
          pa[qt] = *(const bf16x8*)(Pw + (qt * 16 + lan) * 72 + grp * 8 + ks * 32);
#pragma unroll
        for (int hf = 0; hf < 4; ++hf)
          vb[hf] = *(const bf16x8*)(Vc + (hf * 16 + lan) * 64 + (((grp + ks * 4) ^ l7) << 3));
#pragma unroll
        for (int qt = 0; qt < 2; ++qt)
#pragma unroll
          for (int hf = 0; hf < 4; ++hf)
            o[qt][hf] = mfma16(pa[qt], vb[hf], o[qt][hf]);
      }
      __builtin_amdgcn_s_setprio(0);
    }
    __builtin_amdgcn_s_barrier();
  }
#undef STAGE

  // psum: reduce over grp (lanes sharing lan); q = qt*16+lan
#pragma unroll
  for (int qt = 0; qt < 2; ++qt) {
    psum[qt] += __shfl_xor(psum[qt], 16);
    psum[qt] += __shfl_xor(psum[qt], 32);
  }

  if (qq == 2) {
    // final: o = (o_causal + SufV) / (psum + (2047-q))
    const size_t outbase = (size_t)(hd >> 4) * S_ * (N_ * H_) + (size_t)(hd & 15) * H_;
#pragma unroll
    for (int qt = 0; qt < 2; ++qt) {
#pragma unroll
      for (int r = 0; r < 4; ++r) {
        const int q_g = qw + qt * 16 + grp * 4 + r;
        const float ps = __shfl(psum[qt], grp * 4 + r);
        const float inv = 1.0f / (ps + (float)(2047 - q_g));
#pragma unroll
        for (int hf = 0; hf < 4; ++hf) {
          const int h = hf * 16 + lan;
          const float suf = (float)Sufh[(size_t)q_g * H_ + h];
          Wtd[outbase + (size_t)q_g * (N_ * H_) + h] = (bf16)((o[qt][hf][r] + suf) * inv);
        }
      }
    }
  } else {
    // partial: raw fp32 o + row psums
    float* Po = (qq == 0) ? PoA : PoB;
    float* Pp = (qq == 0) ? PpA : PpB;
    const int pb = (hd * 8 + (x - 8)) * 128 + w * 32;
#pragma unroll
    for (int qt = 0; qt < 2; ++qt) {
#pragma unroll
      for (int r = 0; r < 4; ++r) {
        const int rl = qt * 16 + grp * 4 + r;
        const float ps = __shfl(psum[qt], grp * 4 + r);
        if (lan == 0) Pp[pb + rl] = ps;
#pragma unroll
        for (int hf = 0; hf < 4; ++hf)
          Po[(size_t)(pb + rl) * 64 + hf * 16 + lan] = o[qt][hf][r];
      }
    }
  }
}

// ---------------------------------------------------------------------------
// Combine: for x in 8..15, Wtd = (PoA + PoB + Suf) / (PpA + PpB + 2047-q).
// ---------------------------------------------------------------------------
__global__ __launch_bounds__(256) void combine_kernel(
    const float* __restrict__ PoA, const float* __restrict__ PoB,
    const float* __restrict__ PpA, const float* __restrict__ PpB,
    const bf16* __restrict__ Suf, bf16* __restrict__ Wtd) {
  const int hd = blockIdx.x >> 3, xi = blockIdx.x & 7;
  const int x = xi + 8;
  const int pb = (hd * 8 + xi) * 128;
  const size_t outbase = (size_t)(hd >> 4) * S_ * (N_ * H_) + (size_t)(hd & 15) * H_;
#pragma unroll
  for (int it = 0; it < 8; ++it) {
    const int e = it * 256 + threadIdx.x;  // 0..2047 float4 units
    const int rl = e >> 4, h4 = (e & 15) * 4;
    const int q_g = x * 128 + rl;
    const float Z = PpA[pb + rl] + PpB[pb + rl] + (float)(2047 - q_g);
    const float inv = 1.0f / Z;
    const float4 a = *(const float4*)(PoA + (size_t)(pb + rl) * 64 + h4);
    const float4 b = *(const float4*)(PoB + (size_t)(pb + rl) * 64 + h4);
    const bf16x4 s4 = *(const bf16x4*)(Suf + ((size_t)hd * S_ + q_g) * 64 + h4);
    bf16x4 ov;
    ov[0] = (bf16)((a.x + b.x + (float)s4[0]) * inv);
    ov[1] = (bf16)((a.y + b.y + (float)s4[1]) * inv);
    ov[2] = (bf16)((a.z + b.z + (float)s4[2]) * inv);
    ov[3] = (bf16)((a.w + b.w + (float)s4[3]) * inv);
    *(bf16x4*)(Wtd + outbase + (size_t)q_g * (N_ * H_) + h4) = ov;
  }
}

// ---------------------------------------------------------------------------
extern "C" void kernel_launch(void* const* d_in, const int* in_sizes, int n_in,
                              void* d_out, int out_size, void* d_ws, size_t ws_size,
                              hipStream_t stream) {
  const float* residual = (const float*)d_in[0];
  const float* Wk = (const float*)d_in[1];
  const float* Wq = (const float*)d_in[2];
  const float* Wv = (const float*)d_in[3];
  const float* Wo = (const float*)d_in[4];
  const float* Bk = (const float*)d_in[5];
  const float* Bq = (const float*)d_in[6];
  const float* Bv = (const float*)d_in[7];
  const float* Bo = (const float*)d_in[8];
  float* outp = (float*)d_out;

  // ws layout (peak 48MB — proven safe; do NOT exceed):
  //   [ 0.. 8) Abf (cvt out, gemm_proj A)        -> Wtd (attn/combine out)
  //   [ 8..10) Wot (live to end)
  //   [10..16) Wkt (gemm_proj B, [3072][1024])   -> PpA, PpB, tot
  //   [16..24) Kp   [24..32) Qp
  //   [32..40) Vp (proj V) -> in-place Suf (bf16) via sufv_scan
  //   [40..48) Vtp
  // d_out (16MB fp32): PoA [0..8MB) + PoB [8..16MB) until gemm_out overwrites.
  char* ws = (char*)d_ws;
  const size_t MB = 1024 * 1024;
  bf16* Abf = (bf16*)(ws + 0 * MB);
  bf16* Wot = (bf16*)(ws + 8 * MB);
  bf16* Wkt = (bf16*)(ws + 10 * MB);
  bf16* Kp  = (bf16*)(ws + 16 * MB);
  bf16* Qp  = (bf16*)(ws + 24 * MB);
  bf16* Vp  = (bf16*)(ws + 32 * MB);
  bf16* Vtp = (bf16*)(ws + 40 * MB);
  bf16* Wtd = Abf;                                   // dead after gemm_proj
  float* PpA = (float*)(ws + 10 * MB);               // [32][8][128] (128KB)
  float* PpB = (float*)(ws + 10 * MB + 128 * 1024);  // (128KB)
  float* tot = (float*)(ws + 10 * MB + 256 * 1024);  // [32][64][64] (512KB)
  bf16* Suf = Vp;                                    // in-place over Vp
  float* PoA = (float*)d_out;                        // [32][8][128][64] (8MB)
  float* PoB = (float*)d_out + 2 * 1024 * 1024;      // (8MB)
  (void)in_sizes; (void)n_in; (void)out_size; (void)ws_size;

  // residual fp32 -> bf16
  cvt_kernel<<<2048, 256, 0, stream>>>(residual, Abf, (B_ * S_ * D_) / 8);

  // weight transposes
  qkvw_transpose_kernel<<<dim3(16, 1, 48), 256, 0, stream>>>(Wk, Wq, Wv, Wkt);
  transpose_f32bf16_kernel<<<dim3(16, 16, 1), 256, 0, stream>>>(Wo, Wot, 1024, 1024);

  // QKV projections — 256² phase-interleaved kernel, grid (12,16), 512 thr
  gemm_proj_kernel<<<dim3(12, 16), 512, 0, stream>>>(Abf, Wkt, Bk, Bq, Bv, Kp);

  // V consumers BEFORE the in-place suffix scan:
  sufv_tot_kernel<<<dim3(32, 64), 256, 0, stream>>>(Vp, tot);
  transpose_bf16_kernel<<<dim3(32, 1, 32), 256, 0, stream>>>(Vp, Vtp, 2048, 64);
  // in-place: Vp becomes Suf (bf16)
  sufv_scan_kernel<<<dim3(32, 64), 64, 0, stream>>>(Vp, tot);

  // attention: split-k, balanced (34 tiles per CU triple)
  attn_kernel<<<768, 256, 0, stream>>>(Qp, Kp, Vtp, Suf, Wtd, PoA, PoB, PpA, PpB);

  // combine halves for x >= 8
  combine_kernel<<<256, 256, 0, stream>>>(PoA, PoB, PpA, PpB, Suf, Wtd);

  // output projection -> fp32 d_out (overwrites PoA/PoB scratch)
  gemm_out_kernel<<<dim3(8, 32, 1), 256, 0, stream>>>(Wtd, Wot, Bo, outp);
}